// Round 10
// baseline (50048.068 us; speedup 1.0000x reference)
//
#include <hip/hip_runtime.h>
#include <stdint.h>

// ---------------- problem constants ----------------
#define TN    2048      // time steps
#define NBLK  128       // 4 groups x 32 blocks; group = bid&3 (XCD pairs {g,g+4})

// Each block: 16 cell-1 cols + 16 cell-2 cols of one 64-row batch tile.
// 4 waves x 16 rows. Unit k: phase2(k-1) -> phase1(k) -> store h1,h0 ->
// single publish -> single poll -> batch-load next fragments (IF latency paid once).
//
// LDS layout (identical to R7, proven):
#define W1STRIDE 524
#define RZSTRIDE 1036
#define NSTRIDE  524
#define W2RZ_OFF 25152          // elems: 48*524
#define W2N_OFF  58304          // elems: W2RZ_OFF + 32*1036
#define SX_OFF   150144         // bytes
#define FMISC_OFF 152192        // bytes
#define SMEM_BYTES 153600

// ws layout:
//   0       : h0x bf16 [4 slots][256][512]   (1 MiB)   slot(t)=t&3; t=-1 -> slot 3
//   1048576 : h1x bf16 [4 slots][256][512]   (1 MiB)
//   2097152 : counters; group g at +g*256: u32 C (one publish per block per unit)
#define H0_OFF  0
#define H1_OFF  1048576
#define CNT_OFF 2097152

typedef __attribute__((ext_vector_type(8))) short bf16x8;
typedef __attribute__((ext_vector_type(4))) float f32x4;

__device__ __forceinline__ float sigf(float v)   { return 1.0f / (1.0f + __expf(-v)); }
__device__ __forceinline__ float tanhf_(float v) { return 2.0f / (1.0f + __expf(-2.0f * v)) - 1.0f; }
__device__ __forceinline__ unsigned short f2bf(float f) {
  unsigned u = __float_as_uint(f);
  u += 0x7fffu + ((u >> 16) & 1u);   // RNE
  return (unsigned short)(u >> 16);
}

// Agent-scope (IF coherence point) 16B fragment load -- proven correct R6/R7.
__device__ __forceinline__ bf16x8 ld_coh16(const unsigned short* p) {
  union { unsigned long long q[2]; bf16x8 v; } u;
  u.q[0] = __hip_atomic_load((const unsigned long long*)p,
                             __ATOMIC_RELAXED, __HIP_MEMORY_SCOPE_AGENT);
  u.q[1] = __hip_atomic_load((const unsigned long long*)p + 1,
                             __ATOMIC_RELAXED, __HIP_MEMORY_SCOPE_AGENT);
  return u.v;
}

// Re-run safe init: state mirrors (slot 3), out = b_out, counters = 0.
extern "C" __global__ void gru_init(const float* __restrict__ h0,
                                    const float* __restrict__ h1,
                                    const float* __restrict__ b_out,
                                    float* __restrict__ out,
                                    char* __restrict__ ws) {
  int i = blockIdx.x * 256 + threadIdx.x;     // 512 blocks
  unsigned short* h0x = (unsigned short*)(ws + H0_OFF);
  unsigned short* h1x = (unsigned short*)(ws + H1_OFF);
  h0x[3 * 131072 + i] = f2bf(h0[i]);
  h1x[3 * 131072 + i] = f2bf(h1[i]);
  if (blockIdx.x == 0) out[threadIdx.x] = b_out[0];
  if (blockIdx.x == 1) ((unsigned*)(ws + CNT_OFF))[threadIdx.x] = 0u;  // covers 4*256B
}

extern "C" __global__ void __launch_bounds__(256, 1)
gru_main(const float* __restrict__ x,
         const float* __restrict__ W_ih1, const float* __restrict__ W_hh1,
         const float* __restrict__ b_ih1, const float* __restrict__ b_hh1,
         const float* __restrict__ W_ih2, const float* __restrict__ W_hh2,
         const float* __restrict__ b_ih2, const float* __restrict__ b_hh2,
         const float* __restrict__ W_out, const float* __restrict__ b_out,
         const float* __restrict__ h0in, const float* __restrict__ h1in,
         float* __restrict__ out, char* __restrict__ ws)
{
  extern __shared__ char smem[];
  unsigned short* wlds1 = (unsigned short*)smem;
  unsigned short* w2rz  = (unsigned short*)smem + W2RZ_OFF;
  unsigned short* w2n   = (unsigned short*)smem + W2N_OFF;
  unsigned short* sxu   = (unsigned short*)(smem + SX_OFF);
  float* fmisc          = (float*)(smem + FMISC_OFF);

  unsigned short* h0x = (unsigned short*)(ws + H0_OFF);
  unsigned short* h1x = (unsigned short*)(ws + H1_OFF);

  const int bid = blockIdx.x, tid = threadIdx.x;
  const int wv = tid >> 6, l = tid & 63, l15 = l & 15, l4 = l >> 4;

  // group mapping (R7-proven): group g = bids with bid%4==g
  const int bt  = bid & 3;          // group = batch tile (64 rows)
  const int sub = bid >> 2;         // 0..31 within group
  const int S1 = sub * 16, S2 = sub * 16;

  unsigned* cnt = (unsigned*)(ws + CNT_OFF + bt * 256);   // single counter C

  // ---------------- weight preload into LDS (bf16) ----------------
  for (int idx = tid; idx < 48 * 512; idx += 256) {
    int j = idx >> 9, kk = idx & 511;
    int g = j >> 4, c = j & 15;
    wlds1[j * W1STRIDE + kk] = f2bf(W_hh1[(g * 512 + S1 + c) * 512 + kk]);
  }
  for (int idx = tid; idx < 32 * 1024; idx += 256) {
    int j = idx >> 10, kk = idx & 1023;
    int g2 = j >> 4, c = j & 15;
    float v = (kk < 512) ? W_ih2[(g2 * 512 + S2 + c) * 512 + kk]
                         : W_hh2[(g2 * 512 + S2 + c) * 512 + kk - 512];
    w2rz[j * RZSTRIDE + kk] = f2bf(v);
  }
  for (int idx = tid; idx < 32 * 512; idx += 256) {
    int j = idx >> 9, kk = idx & 511;
    int t = j >> 4, c = j & 15;
    const float* Wsrc = t ? W_hh2 : W_ih2;
    w2n[j * NSTRIDE + kk] = f2bf(Wsrc[(1024 + S2 + c) * 512 + kk]);
  }
  if (tid < 48) {
    int g = tid >> 4, c = tid & 15;
    int grow = g * 512 + S1 + c;
    fmisc[tid]      = W_ih1[grow];
    fmisc[48 + tid] = b_ih1[grow];
    fmisc[96 + tid] = b_hh1[grow];
  } else if (tid < 144) {
    int t = tid - 48;
    int g = t >> 4, c = t & 15;
    float v;
    if      (g == 0) v = b_ih2[S2 + c];
    else if (g == 1) v = b_ih2[512 + S2 + c];
    else if (g == 2) v = b_ih2[1024 + S2 + c];
    else if (g == 3) v = b_hh2[S2 + c];
    else if (g == 4) v = b_hh2[512 + S2 + c];
    else             v = b_hh2[1024 + S2 + c];
    fmisc[144 + t] = v;
  }
  __syncthreads();

  // ---------------- per-thread constants / carries ----------------
  int rowD[4];
  #pragma unroll
  for (int q = 0; q < 4; ++q) rowD[q] = bt * 64 + wv * 16 + l4 * 4 + q;
  const int arow = (wv * 16 + l15) * 512;

  float c0[4], c1[4];
  #pragma unroll
  for (int q = 0; q < 4; ++q) {
    c0[q] = h0in[rowD[q] * 512 + S1 + l15];
    c1[q] = h1in[rowD[q] * 512 + S2 + l15];
  }
  const float wout = W_out[S2 + l15];

  const float wir = fmisc[l15],      wiz = fmisc[16 + l15],  win = fmisc[32 + l15];
  const float bir = fmisc[48 + l15], biz = fmisc[64 + l15],  bin = fmisc[80 + l15];
  const float bhr = fmisc[96 + l15], bhz = fmisc[112 + l15], bhn = fmisc[128 + l15];
  const float bir2 = fmisc[144 + l15], biz2 = fmisc[160 + l15], bin2 = fmisc[176 + l15];
  const float bhr2 = fmisc[192 + l15], bhz2 = fmisc[208 + l15], bhn2 = fmisc[224 + l15];

  int dead = 0;   // only tid0's copy matters

  auto st_coh = [&](unsigned short* p, unsigned long long v) {
    __hip_atomic_store((unsigned long long*)p, v, __ATOMIC_RELAXED, __HIP_MEMORY_SCOPE_AGENT);
  };

  // ---------------- prologue: fragsH0 = h0(-1) (slot 3) ----------------
  bf16x8 fH0[16], fH1[16];
  {
    const unsigned short* s = h0x + 3 * 131072 + bt * 32768;
    #pragma unroll
    for (int ks = 0; ks < 16; ++ks) fH0[ks] = ld_coh16(s + arow + ks * 32 + l4 * 8);
  }

  // ---------------- unit loop: unit k = phase2(k-1) + phase1(k) ----------------
  for (int k = 0; k <= TN; ++k) {
    float xv[4];
    if (k < TN) {
      #pragma unroll
      for (int q = 0; q < 4; ++q) xv[q] = x[rowD[q] * 2048 + k];   // issue early
    }

    // ========== phase 2 (k-1): h1(k-1) = GRU2(h0(k-1), h1(k-2)) ==========
    if (k >= 1) {
      f32x4 a2[4];
      #pragma unroll
      for (int g = 0; g < 4; ++g) a2[g] = f32x4{0.f, 0.f, 0.f, 0.f};

      #pragma unroll
      for (int ks = 0; ks < 16; ++ks) {          // K 0..511: h0(k-1) operand (in regs)
        #pragma unroll
        for (int g2 = 0; g2 < 2; ++g2) {
          bf16x8 bw = *(const bf16x8*)(w2rz + (g2 * 16 + l15) * RZSTRIDE + ks * 32 + l4 * 8);
          a2[g2] = __builtin_amdgcn_mfma_f32_16x16x32_bf16(fH0[ks], bw, a2[g2], 0, 0, 0);
        }
        bf16x8 bn = *(const bf16x8*)(w2n + l15 * NSTRIDE + ks * 32 + l4 * 8);
        a2[2] = __builtin_amdgcn_mfma_f32_16x16x32_bf16(fH0[ks], bn, a2[2], 0, 0, 0);
      }
      #pragma unroll
      for (int ks2 = 0; ks2 < 16; ++ks2) {       // K 512..1023: h1(k-2) operand (in regs)
        #pragma unroll
        for (int g2 = 0; g2 < 2; ++g2) {
          bf16x8 bw = *(const bf16x8*)(w2rz + (g2 * 16 + l15) * RZSTRIDE + (16 + ks2) * 32 + l4 * 8);
          a2[g2] = __builtin_amdgcn_mfma_f32_16x16x32_bf16(fH1[ks2], bw, a2[g2], 0, 0, 0);
        }
        bf16x8 bh = *(const bf16x8*)(w2n + (16 + l15) * NSTRIDE + ks2 * 32 + l4 * 8);
        a2[3] = __builtin_amdgcn_mfma_f32_16x16x32_bf16(fH1[ks2], bh, a2[3], 0, 0, 0);
      }

      #pragma unroll
      for (int q = 0; q < 4; ++q) {
        float rg = sigf(a2[0][q] + bir2 + bhr2);
        float zg = sigf(a2[1][q] + biz2 + bhz2);
        float ng = tanhf_(a2[2][q] + bin2 + rg * (a2[3][q] + bhn2));
        float hv = (1.0f - zg) * ng + zg * c1[q];
        c1[q] = hv;
        sxu[(wv * 16 + l4 * 4 + q) * 16 + l15] = f2bf(hv);
        if (k - 1 == TN - 1) atomicAdd(&out[rowD[q]], hv * wout);   // final projection
      }
      __syncthreads();
      {
        unsigned long long v = ((const unsigned long long*)sxu)[tid];
        unsigned short* dst = h1x + ((k - 1) & 3) * 131072
                            + (bt * 64 + (tid >> 2)) * 512 + S2 + (tid & 3) * 4;
        st_coh(dst, v);
      }
    }

    if (k < TN) {
      // ========== phase 1 (k): h0(k) = GRU1(x(k), h0(k-1)) -- zero global loads ==========
      f32x4 a1[3];
      #pragma unroll
      for (int g = 0; g < 3; ++g) a1[g] = f32x4{0.f, 0.f, 0.f, 0.f};

      #pragma unroll
      for (int ks = 0; ks < 16; ++ks) {
        #pragma unroll
        for (int g = 0; g < 3; ++g) {
          bf16x8 bw = *(const bf16x8*)(wlds1 + (g * 16 + l15) * W1STRIDE + ks * 32 + l4 * 8);
          a1[g] = __builtin_amdgcn_mfma_f32_16x16x32_bf16(fH0[ks], bw, a1[g], 0, 0, 0);
        }
      }

      __syncthreads();   // all h1-store reads of sxu complete before rewrite
      #pragma unroll
      for (int q = 0; q < 4; ++q) {
        float rg = sigf(xv[q] * wir + bir + a1[0][q] + bhr);
        float zg = sigf(xv[q] * wiz + biz + a1[1][q] + bhz);
        float ng = tanhf_(xv[q] * win + bin + rg * (a1[2][q] + bhn));
        float hv = (1.0f - zg) * ng + zg * c0[q];
        c0[q] = hv;
        sxu[(wv * 16 + l4 * 4 + q) * 16 + l15] = f2bf(hv);
      }
      __syncthreads();
      {
        unsigned long long v = ((const unsigned long long*)sxu)[tid];
        unsigned short* dst = h0x + (k & 3) * 131072
                            + (bt * 64 + (tid >> 2)) * 512 + S1 + (tid & 3) * 4;
        st_coh(dst, v);
      }

      // ========== drain + single publish ==========
      asm volatile("s_waitcnt vmcnt(0)" ::: "memory");
      __syncthreads();
      if (tid == 0)
        __hip_atomic_fetch_add(cnt, 1u, __ATOMIC_RELAXED, __HIP_MEMORY_SCOPE_AGENT);

      // ========== single poll: all h0(k) + h1(k-1) published ==========
      if (tid == 0 && !dead) {
        unsigned tgt = 32u * (unsigned)(k + 1);
        int spins = 0;
        while (__hip_atomic_load(cnt, __ATOMIC_RELAXED, __HIP_MEMORY_SCOPE_AGENT) < tgt) {
          __builtin_amdgcn_s_sleep(2);
          if (++spins > 1000000) { dead = 1; break; }   // bounded failure, no hang
        }
      }
      __syncthreads();

      // ========== batch-load next unit's fragments (one IF latency) ==========
      const unsigned short* s0 = h0x + (k & 3) * 131072 + bt * 32768;       // h0(k)
      const unsigned short* s1 = h1x + ((k + 3) & 3) * 131072 + bt * 32768; // h1(k-1)
      #pragma unroll
      for (int ks = 0; ks < 16; ++ks) fH0[ks] = ld_coh16(s0 + arow + ks * 32 + l4 * 8);
      #pragma unroll
      for (int ks = 0; ks < 16; ++ks) fH1[ks] = ld_coh16(s1 + arow + ks * 32 + l4 * 8);
      // compiler-tracked vmcnt waits sink to first use (next unit's MFMAs)
    }
  }
}

extern "C" void kernel_launch(void* const* d_in, const int* in_sizes, int n_in,
                              void* d_out, int out_size, void* d_ws, size_t ws_size,
                              hipStream_t stream) {
  const float* x     = (const float*)d_in[0];
  const float* h0in  = (const float*)d_in[1];
  const float* h1in  = (const float*)d_in[2];
  const float* W_ih1 = (const float*)d_in[3];
  const float* W_hh1 = (const float*)d_in[4];
  const float* b_ih1 = (const float*)d_in[5];
  const float* b_hh1 = (const float*)d_in[6];
  const float* W_ih2 = (const float*)d_in[7];
  const float* W_hh2 = (const float*)d_in[8];
  const float* b_ih2 = (const float*)d_in[9];
  const float* b_hh2 = (const float*)d_in[10];
  const float* W_out = (const float*)d_in[11];
  const float* b_out = (const float*)d_in[12];
  float* out = (float*)d_out;
  char* ws = (char*)d_ws;

  (void)in_sizes; (void)n_in; (void)out_size; (void)ws_size;

  hipFuncSetAttribute((const void*)gru_main,
                      hipFuncAttributeMaxDynamicSharedMemorySize, SMEM_BYTES);

  hipLaunchKernelGGL(gru_init, dim3(512), dim3(256), 0, stream,
                     h0in, h1in, b_out, out, ws);

  void* args[] = { (void*)&x,
                   (void*)&W_ih1, (void*)&W_hh1, (void*)&b_ih1, (void*)&b_hh1,
                   (void*)&W_ih2, (void*)&W_hh2, (void*)&b_ih2, (void*)&b_hh2,
                   (void*)&W_out, (void*)&b_out,
                   (void*)&h0in, (void*)&h1in,
                   (void*)&out, (void*)&ws };
  hipLaunchCooperativeKernel((const void*)gru_main, dim3(NBLK), dim3(256),
                             args, SMEM_BYTES, stream);
}

// Round 11
// 45716.336 us; speedup vs baseline: 1.0948x; 1.0948x over previous
//
#include <hip/hip_runtime.h>
#include <stdint.h>

// ---------------- problem constants ----------------
#define TN    2048      // time steps
#define NBLK  128       // 4 groups x 32 blocks; group = bid&3

// Each block: 16 cell-1 cols + 16 cell-2 cols of one 64-row batch tile.
// Unit k: phase1(k) -> publish F0 -> phase2(k-1) -> publish F1 ->
//         poll F0 (hidden under phase2) -> load fH0 -> poll F1 -> load fH1.
// Flags are per-block (contention-free); polls are lane-parallel (32 lanes).
//
// LDS layout (identical to R7/R10, proven):
#define W1STRIDE 524
#define RZSTRIDE 1036
#define NSTRIDE  524
#define W2RZ_OFF 25152          // elems: 48*524
#define W2N_OFF  58304          // elems: W2RZ_OFF + 32*1036
#define SX_OFF   150144         // bytes
#define FMISC_OFF 152192        // bytes
#define SMEM_BYTES 153600

// ws layout:
//   0       : h0x bf16 [4 slots][256][512]   (1 MiB)   slot(t)=t&3; t=-1 -> slot 3
//   1048576 : h1x bf16 [4 slots][256][512]   (1 MiB)
//   2097152 : F0 flags u32, 64B stride: group g at +g*4096, block sub at +sub*64
//   2113536 : F1 flags u32, same layout (CNT_OFF + 16384)
#define H0_OFF  0
#define H1_OFF  1048576
#define CNT_OFF 2097152

typedef __attribute__((ext_vector_type(8))) short bf16x8;
typedef __attribute__((ext_vector_type(4))) float f32x4;

__device__ __forceinline__ float sigf(float v)   { return 1.0f / (1.0f + __expf(-v)); }
__device__ __forceinline__ float tanhf_(float v) { return 2.0f / (1.0f + __expf(-2.0f * v)) - 1.0f; }
__device__ __forceinline__ unsigned short f2bf(float f) {
  unsigned u = __float_as_uint(f);
  u += 0x7fffu + ((u >> 16) & 1u);   // RNE
  return (unsigned short)(u >> 16);
}

// Agent-scope (IF coherence point) 16B fragment load -- proven R6/R7/R10.
__device__ __forceinline__ bf16x8 ld_coh16(const unsigned short* p) {
  union { unsigned long long q[2]; bf16x8 v; } u;
  u.q[0] = __hip_atomic_load((const unsigned long long*)p,
                             __ATOMIC_RELAXED, __HIP_MEMORY_SCOPE_AGENT);
  u.q[1] = __hip_atomic_load((const unsigned long long*)p + 1,
                             __ATOMIC_RELAXED, __HIP_MEMORY_SCOPE_AGENT);
  return u.v;
}

// Re-run safe init: state mirrors (slot 3), out = b_out, flags = 0.
extern "C" __global__ void gru_init(const float* __restrict__ h0,
                                    const float* __restrict__ h1,
                                    const float* __restrict__ b_out,
                                    float* __restrict__ out,
                                    char* __restrict__ ws) {
  int i = blockIdx.x * 256 + threadIdx.x;     // 512 blocks
  unsigned short* h0x = (unsigned short*)(ws + H0_OFF);
  unsigned short* h1x = (unsigned short*)(ws + H1_OFF);
  h0x[3 * 131072 + i] = f2bf(h0[i]);
  h1x[3 * 131072 + i] = f2bf(h1[i]);
  if (blockIdx.x == 0) out[threadIdx.x] = b_out[0];
  if (blockIdx.x >= 1 && blockIdx.x <= 32)    // zero 32 KB of flags
    ((unsigned*)(ws + CNT_OFF))[(blockIdx.x - 1) * 256 + threadIdx.x] = 0u;
}

extern "C" __global__ void __launch_bounds__(256, 1)
gru_main(const float* __restrict__ x,
         const float* __restrict__ W_ih1, const float* __restrict__ W_hh1,
         const float* __restrict__ b_ih1, const float* __restrict__ b_hh1,
         const float* __restrict__ W_ih2, const float* __restrict__ W_hh2,
         const float* __restrict__ b_ih2, const float* __restrict__ b_hh2,
         const float* __restrict__ W_out, const float* __restrict__ b_out,
         const float* __restrict__ h0in, const float* __restrict__ h1in,
         float* __restrict__ out, char* __restrict__ ws)
{
  extern __shared__ char smem[];
  unsigned short* wlds1 = (unsigned short*)smem;
  unsigned short* w2rz  = (unsigned short*)smem + W2RZ_OFF;
  unsigned short* w2n   = (unsigned short*)smem + W2N_OFF;
  unsigned short* sxu   = (unsigned short*)(smem + SX_OFF);
  float* fmisc          = (float*)(smem + FMISC_OFF);

  unsigned short* h0x = (unsigned short*)(ws + H0_OFF);
  unsigned short* h1x = (unsigned short*)(ws + H1_OFF);

  const int bid = blockIdx.x, tid = threadIdx.x;
  const int wv = tid >> 6, l = tid & 63, l15 = l & 15, l4 = l >> 4;

  const int bt  = bid & 3;          // group = batch tile (64 rows)
  const int sub = bid >> 2;         // 0..31 within group
  const int S1 = sub * 16, S2 = sub * 16;

  unsigned* F0g = (unsigned*)(ws + CNT_OFF)         + bt * 1024;  // 4096 B per group
  unsigned* F1g = (unsigned*)(ws + CNT_OFF + 16384) + bt * 1024;
  unsigned* myF0 = F0g + sub * 16;   // 64 B stride
  unsigned* myF1 = F1g + sub * 16;

  // ---------------- weight preload into LDS (bf16) ----------------
  for (int idx = tid; idx < 48 * 512; idx += 256) {
    int j = idx >> 9, kk = idx & 511;
    int g = j >> 4, c = j & 15;
    wlds1[j * W1STRIDE + kk] = f2bf(W_hh1[(g * 512 + S1 + c) * 512 + kk]);
  }
  for (int idx = tid; idx < 32 * 1024; idx += 256) {
    int j = idx >> 10, kk = idx & 1023;
    int g2 = j >> 4, c = j & 15;
    float v = (kk < 512) ? W_ih2[(g2 * 512 + S2 + c) * 512 + kk]
                         : W_hh2[(g2 * 512 + S2 + c) * 512 + kk - 512];
    w2rz[j * RZSTRIDE + kk] = f2bf(v);
  }
  for (int idx = tid; idx < 32 * 512; idx += 256) {
    int j = idx >> 9, kk = idx & 511;
    int t = j >> 4, c = j & 15;
    const float* Wsrc = t ? W_hh2 : W_ih2;
    w2n[j * NSTRIDE + kk] = f2bf(Wsrc[(1024 + S2 + c) * 512 + kk]);
  }
  if (tid < 48) {
    int g = tid >> 4, c = tid & 15;
    int grow = g * 512 + S1 + c;
    fmisc[tid]      = W_ih1[grow];
    fmisc[48 + tid] = b_ih1[grow];
    fmisc[96 + tid] = b_hh1[grow];
  } else if (tid < 144) {
    int t = tid - 48;
    int g = t >> 4, c = t & 15;
    float v;
    if      (g == 0) v = b_ih2[S2 + c];
    else if (g == 1) v = b_ih2[512 + S2 + c];
    else if (g == 2) v = b_ih2[1024 + S2 + c];
    else if (g == 3) v = b_hh2[S2 + c];
    else if (g == 4) v = b_hh2[512 + S2 + c];
    else             v = b_hh2[1024 + S2 + c];
    fmisc[144 + t] = v;
  }
  __syncthreads();

  // ---------------- per-thread constants / carries ----------------
  int rowD[4];
  #pragma unroll
  for (int q = 0; q < 4; ++q) rowD[q] = bt * 64 + wv * 16 + l4 * 4 + q;
  const int arow = (wv * 16 + l15) * 512;

  float c0[4], c1[4];
  #pragma unroll
  for (int q = 0; q < 4; ++q) {
    c0[q] = h0in[rowD[q] * 512 + S1 + l15];
    c1[q] = h1in[rowD[q] * 512 + S2 + l15];
  }
  const float wout = W_out[S2 + l15];

  const float wir = fmisc[l15],      wiz = fmisc[16 + l15],  win = fmisc[32 + l15];
  const float bir = fmisc[48 + l15], biz = fmisc[64 + l15],  bin = fmisc[80 + l15];
  const float bhr = fmisc[96 + l15], bhz = fmisc[112 + l15], bhn = fmisc[128 + l15];
  const float bir2 = fmisc[144 + l15], biz2 = fmisc[160 + l15], bin2 = fmisc[176 + l15];
  const float bhr2 = fmisc[192 + l15], bhz2 = fmisc[208 + l15], bhn2 = fmisc[224 + l15];

  int dead = 0;   // wave-0 lanes' copy matters (polls are wave-0 only)

  auto st_coh = [&](unsigned short* p, unsigned long long v) {
    __hip_atomic_store((unsigned long long*)p, v, __ATOMIC_RELAXED, __HIP_MEMORY_SCOPE_AGENT);
  };
  // drain own stores, block-wide rendezvous, then one contention-free flag store
  auto publish = [&](unsigned* fl, unsigned val) {
    asm volatile("s_waitcnt vmcnt(0)" ::: "memory");
    __syncthreads();
    if (tid == 0)
      __hip_atomic_store(fl, val, __ATOMIC_RELAXED, __HIP_MEMORY_SCOPE_AGENT);
  };
  // lane-parallel group barrier check: lanes 0..31 of wave 0 each watch one flag
  auto group_poll = [&](const unsigned* fbase, unsigned tgt) {
    if (wv == 0 && !dead) {
      int spins = 0;
      for (;;) {
        unsigned v = tgt;
        if (l < 32)
          v = __hip_atomic_load(fbase + l * 16, __ATOMIC_RELAXED, __HIP_MEMORY_SCOPE_AGENT);
        if (__all(v >= tgt)) break;
        __builtin_amdgcn_s_sleep(1);
        if (++spins > 300000) { dead = 1; break; }   // bounded failure, no hang
      }
    }
    __syncthreads();
  };

  // ---------------- prologue: fH0 = h0(-1) (slot 3) ----------------
  bf16x8 fH0[16], fH1[16];
  {
    const unsigned short* s = h0x + 3 * 131072 + bt * 32768;
    #pragma unroll
    for (int ks = 0; ks < 16; ++ks) fH0[ks] = ld_coh16(s + arow + ks * 32 + l4 * 8);
    const unsigned short* s1 = h1x + 3 * 131072 + bt * 32768;   // h1(-1), used at unit 1
    #pragma unroll
    for (int ks = 0; ks < 16; ++ks) fH1[ks] = ld_coh16(s1 + arow + ks * 32 + l4 * 8);
  }

  // ---------------- unit loop ----------------
  for (int k = 0; k <= TN; ++k) {
    // ========== phase 1 (k): h0(k) = GRU1(x(k), h0(k-1)=fH0) ==========
    if (k < TN) {
      float xv[4];
      #pragma unroll
      for (int q = 0; q < 4; ++q) xv[q] = x[rowD[q] * 2048 + k];

      f32x4 a1[3];
      #pragma unroll
      for (int g = 0; g < 3; ++g) a1[g] = f32x4{0.f, 0.f, 0.f, 0.f};

      #pragma unroll
      for (int ks = 0; ks < 16; ++ks) {
        #pragma unroll
        for (int g = 0; g < 3; ++g) {
          bf16x8 bw = *(const bf16x8*)(wlds1 + (g * 16 + l15) * W1STRIDE + ks * 32 + l4 * 8);
          a1[g] = __builtin_amdgcn_mfma_f32_16x16x32_bf16(fH0[ks], bw, a1[g], 0, 0, 0);
        }
      }
      #pragma unroll
      for (int q = 0; q < 4; ++q) {
        float rg = sigf(xv[q] * wir + bir + a1[0][q] + bhr);
        float zg = sigf(xv[q] * wiz + biz + a1[1][q] + bhz);
        float ng = tanhf_(xv[q] * win + bin + rg * (a1[2][q] + bhn));
        float hv = (1.0f - zg) * ng + zg * c0[q];
        c0[q] = hv;
        sxu[(wv * 16 + l4 * 4 + q) * 16 + l15] = f2bf(hv);
      }
      __syncthreads();
      {
        unsigned long long v = ((const unsigned long long*)sxu)[tid];
        unsigned short* dst = h0x + (k & 3) * 131072
                            + (bt * 64 + (tid >> 2)) * 512 + S1 + (tid & 3) * 4;
        st_coh(dst, v);
      }
      publish(myF0, (unsigned)(k + 1));
    }

    // ========== phase 2 (k-1): h1(k-1) = GRU2(h0(k-1)=fH0, h1(k-2)=fH1) ==========
    if (k >= 1) {
      f32x4 a2[4];
      #pragma unroll
      for (int g = 0; g < 4; ++g) a2[g] = f32x4{0.f, 0.f, 0.f, 0.f};

      #pragma unroll
      for (int ks = 0; ks < 16; ++ks) {          // K 0..511: h0(k-1) operand
        #pragma unroll
        for (int g2 = 0; g2 < 2; ++g2) {
          bf16x8 bw = *(const bf16x8*)(w2rz + (g2 * 16 + l15) * RZSTRIDE + ks * 32 + l4 * 8);
          a2[g2] = __builtin_amdgcn_mfma_f32_16x16x32_bf16(fH0[ks], bw, a2[g2], 0, 0, 0);
        }
        bf16x8 bn = *(const bf16x8*)(w2n + l15 * NSTRIDE + ks * 32 + l4 * 8);
        a2[2] = __builtin_amdgcn_mfma_f32_16x16x32_bf16(fH0[ks], bn, a2[2], 0, 0, 0);
      }
      #pragma unroll
      for (int ks2 = 0; ks2 < 16; ++ks2) {       // K 512..1023: h1(k-2) operand
        #pragma unroll
        for (int g2 = 0; g2 < 2; ++g2) {
          bf16x8 bw = *(const bf16x8*)(w2rz + (g2 * 16 + l15) * RZSTRIDE + (16 + ks2) * 32 + l4 * 8);
          a2[g2] = __builtin_amdgcn_mfma_f32_16x16x32_bf16(fH1[ks2], bw, a2[g2], 0, 0, 0);
        }
        bf16x8 bh = *(const bf16x8*)(w2n + (16 + l15) * NSTRIDE + ks2 * 32 + l4 * 8);
        a2[3] = __builtin_amdgcn_mfma_f32_16x16x32_bf16(fH1[ks2], bh, a2[3], 0, 0, 0);
      }

      #pragma unroll
      for (int q = 0; q < 4; ++q) {
        float rg = sigf(a2[0][q] + bir2 + bhr2);
        float zg = sigf(a2[1][q] + biz2 + bhz2);
        float ng = tanhf_(a2[2][q] + bin2 + rg * (a2[3][q] + bhn2));
        float hv = (1.0f - zg) * ng + zg * c1[q];
        c1[q] = hv;
        sxu[(wv * 16 + l4 * 4 + q) * 16 + l15] = f2bf(hv);
        if (k - 1 == TN - 1) atomicAdd(&out[rowD[q]], hv * wout);   // final projection
      }
      __syncthreads();
      {
        unsigned long long v = ((const unsigned long long*)sxu)[tid];
        unsigned short* dst = h1x + ((k - 1) & 3) * 131072
                            + (bt * 64 + (tid >> 2)) * 512 + S2 + (tid & 3) * 4;
        st_coh(dst, v);
      }
      publish(myF1, (unsigned)k);
    }

    // ========== polls + next-unit fragment loads ==========
    if (k < TN) {
      // F0 was published before phase2 ran -> usually satisfied on first try
      group_poll(F0g, (unsigned)(k + 1));
      const unsigned short* s0 = h0x + (k & 3) * 131072 + bt * 32768;       // h0(k)
      #pragma unroll
      for (int ks = 0; ks < 16; ++ks) fH0[ks] = ld_coh16(s0 + arow + ks * 32 + l4 * 8);

      if (k >= 1) group_poll(F1g, (unsigned)k);  // fH0 load latency hides here
      const unsigned short* s1 = h1x + ((k + 3) & 3) * 131072 + bt * 32768; // h1(k-1)
      #pragma unroll
      for (int ks = 0; ks < 16; ++ks) fH1[ks] = ld_coh16(s1 + arow + ks * 32 + l4 * 8);
    }
  }
}

extern "C" void kernel_launch(void* const* d_in, const int* in_sizes, int n_in,
                              void* d_out, int out_size, void* d_ws, size_t ws_size,
                              hipStream_t stream) {
  const float* x     = (const float*)d_in[0];
  const float* h0in  = (const float*)d_in[1];
  const float* h1in  = (const float*)d_in[2];
  const float* W_ih1 = (const float*)d_in[3];
  const float* W_hh1 = (const float*)d_in[4];
  const float* b_ih1 = (const float*)d_in[5];
  const float* b_hh1 = (const float*)d_in[6];
  const float* W_ih2 = (const float*)d_in[7];
  const float* W_hh2 = (const float*)d_in[8];
  const float* b_ih2 = (const float*)d_in[9];
  const float* b_hh2 = (const float*)d_in[10];
  const float* W_out = (const float*)d_in[11];
  const float* b_out = (const float*)d_in[12];
  float* out = (float*)d_out;
  char* ws = (char*)d_ws;

  (void)in_sizes; (void)n_in; (void)out_size; (void)ws_size;

  hipFuncSetAttribute((const void*)gru_main,
                      hipFuncAttributeMaxDynamicSharedMemorySize, SMEM_BYTES);

  hipLaunchKernelGGL(gru_init, dim3(512), dim3(256), 0, stream,
                     h0in, h1in, b_out, out, ws);

  void* args[] = { (void*)&x,
                   (void*)&W_ih1, (void*)&W_hh1, (void*)&b_ih1, (void*)&b_hh1,
                   (void*)&W_ih2, (void*)&W_hh2, (void*)&b_ih2, (void*)&b_hh2,
                   (void*)&W_out, (void*)&b_out,
                   (void*)&h0in, (void*)&h1in,
                   (void*)&out, (void*)&ws };
  hipLaunchCooperativeKernel((const void*)gru_main, dim3(NBLK), dim3(256),
                             args, SMEM_BYTES, stream);
}

// Round 12
// 43391.013 us; speedup vs baseline: 1.1534x; 1.0536x over previous
//
#include <hip/hip_runtime.h>
#include <stdint.h>

// ---------------- problem constants ----------------
#define TN     2048     // time steps
#define NBLK   192      // 4 groups x (16 A-blocks + 32 B-blocks)  [R6 structure]

// LDS layout (pad strides == 6 mod 32 words -> ~2-way bank aliasing, free):
#define ASTRIDE  524
#define B0STRIDE 1036
#define BSTRIDE  524
#define R1BASE   33152          // 32*1036
#define R2BASE   41536          // R1BASE + 16*524
#define EXCH_OFF  100608
#define SX_OFF    109312
#define FMISC_OFF 113408
#define SMEM_BYTES 114688

// ws layout:
//   0       : h0x bf16 [4 slots][256][512]   (1 MiB)   slot(t)=t&3; t=-1 -> slot 3
//   1048576 : h1x bf16 [4 slots][256][512]   (1 MiB)
//   2097152 : FA flags u32 64B-stride: group g at +g*4096, A-block j at +j*64
//   2113536 : FB flags u32 64B-stride: group g at +g*4096, B-block j at +j*64
#define H0_OFF  0
#define H1_OFF  1048576
#define CNT_OFF 2097152

typedef __attribute__((ext_vector_type(8))) short bf16x8;
typedef __attribute__((ext_vector_type(4))) float f32x4;

__device__ __forceinline__ float sigf(float v)   { return 1.0f / (1.0f + __expf(-v)); }
__device__ __forceinline__ float tanhf_(float v) { return 2.0f / (1.0f + __expf(-2.0f * v)) - 1.0f; }
__device__ __forceinline__ unsigned short f2bf(float f) {
  unsigned u = __float_as_uint(f);
  u += 0x7fffu + ((u >> 16) & 1u);   // RNE
  return (unsigned short)(u >> 16);
}

// Agent-scope (IF coherence point) 16B fragment load -- proven R6/R7/R10/R11.
__device__ __forceinline__ bf16x8 ld_coh16(const unsigned short* p) {
  union { unsigned long long q[2]; bf16x8 v; } u;
  u.q[0] = __hip_atomic_load((const unsigned long long*)p,
                             __ATOMIC_RELAXED, __HIP_MEMORY_SCOPE_AGENT);
  u.q[1] = __hip_atomic_load((const unsigned long long*)p + 1,
                             __ATOMIC_RELAXED, __HIP_MEMORY_SCOPE_AGENT);
  return u.v;
}

// Re-run safe init: state mirrors (slot 3), out = b_out, flags = 0.
extern "C" __global__ void gru_init(const float* __restrict__ h0,
                                    const float* __restrict__ h1,
                                    const float* __restrict__ b_out,
                                    float* __restrict__ out,
                                    char* __restrict__ ws) {
  int i = blockIdx.x * 256 + threadIdx.x;     // 512 blocks
  unsigned short* h0x = (unsigned short*)(ws + H0_OFF);
  unsigned short* h1x = (unsigned short*)(ws + H1_OFF);
  h0x[3 * 131072 + i] = f2bf(h0[i]);
  h1x[3 * 131072 + i] = f2bf(h1[i]);
  if (blockIdx.x == 0) out[threadIdx.x] = b_out[0];
  if (blockIdx.x >= 1 && blockIdx.x <= 32)    // zero 32 KB of flags
    ((unsigned*)(ws + CNT_OFF))[(blockIdx.x - 1) * 256 + threadIdx.x] = 0u;
}

extern "C" __global__ void __launch_bounds__(256, 1)
gru_main(const float* __restrict__ x,
         const float* __restrict__ W_ih1, const float* __restrict__ W_hh1,
         const float* __restrict__ b_ih1, const float* __restrict__ b_hh1,
         const float* __restrict__ W_ih2, const float* __restrict__ W_hh2,
         const float* __restrict__ b_ih2, const float* __restrict__ b_hh2,
         const float* __restrict__ W_out, const float* __restrict__ b_out,
         const float* __restrict__ h0in, const float* __restrict__ h1in,
         float* __restrict__ out, char* __restrict__ ws)
{
  extern __shared__ char smem[];
  unsigned short* wlds = (unsigned short*)smem;
  float* exch  = (float*)(smem + EXCH_OFF);
  unsigned short* sxu = (unsigned short*)(smem + SX_OFF);
  float* fmisc = (float*)(smem + FMISC_OFF);

  unsigned short* h0x = (unsigned short*)(ws + H0_OFF);
  unsigned short* h1x = (unsigned short*)(ws + H1_OFF);

  const int bid = blockIdx.x, tid = threadIdx.x;
  const int w = tid >> 6, l = tid & 63, l15 = l & 15, l4 = l >> 4;
  const int p_ = w >> 1;     // M half: rows 0-31 / 32-63
  const int hh = w & 1;      // A: column half; B: gate role

  // group mapping, XCD-aware (R6-proven)
  const int bt  = (bid & 7) >> 1;
  const int sub = (bid >> 3) * 2 + (bid & 1);
  const bool isA = (sub < 16);
  const int S = isA ? sub * 32 : (sub - 16) * 16;
  const int jA = sub;             // A producer index 0..15
  const int jB = sub - 16;        // B producer index 0..31

  unsigned* FAf = (unsigned*)(ws + CNT_OFF)         + bt * 1024;  // 16 flags, 64B stride
  unsigned* FBf = (unsigned*)(ws + CNT_OFF + 16384) + bt * 1024;  // 32 flags, 64B stride

  // ---------------- weight preload into LDS (bf16)  [R6 verbatim] ----------------
  if (isA) {
    for (int idx = tid; idx < 96 * 512; idx += 256) {
      int j = idx >> 9, kk = idx & 511;
      int h = j / 48, rr = j % 48, g = rr >> 4, c2 = rr & 15;
      int grow = g * 512 + S + h * 16 + c2;
      wlds[j * ASTRIDE + kk] = f2bf(W_hh1[grow * 512 + kk]);
    }
    if (tid < 96) {
      int j = tid, h = j / 48, rr = j % 48, g = rr >> 4, c2 = rr & 15;
      int grow = g * 512 + S + h * 16 + c2;
      fmisc[j]       = W_ih1[grow];
      fmisc[96 + j]  = b_ih1[grow];
      fmisc[192 + j] = b_hh1[grow];
    }
  } else {
    for (int idx = tid; idx < 32 * 1024; idx += 256) {
      int j = idx >> 10, kk = idx & 1023;
      int g = j >> 4, c2 = S + (j & 15);
      float v = (kk < 512) ? W_ih2[(g * 512 + c2) * 512 + kk]
                           : W_hh2[(g * 512 + c2) * 512 + kk - 512];
      wlds[j * B0STRIDE + kk] = f2bf(v);
    }
    for (int idx = tid; idx < 16 * 512; idx += 256) {
      int j2 = idx >> 9, kk = idx & 511;
      wlds[R1BASE + j2 * BSTRIDE + kk] = f2bf(W_ih2[(1024 + S + j2) * 512 + kk]);
      wlds[R2BASE + j2 * BSTRIDE + kk] = f2bf(W_hh2[(1024 + S + j2) * 512 + kk]);
    }
    if (tid < 48) {
      int g = tid >> 4, c2 = S + (tid & 15);
      fmisc[tid]      = b_ih2[g * 512 + c2];
      fmisc[48 + tid] = b_hh2[g * 512 + c2];
    }
  }
  __syncthreads();

  // ---------------- per-thread constants / carries  [R6 verbatim] ----------------
  int rowb[2][4];
  int arowOff[2];
  #pragma unroll
  for (int mtl = 0; mtl < 2; ++mtl) {
    arowOff[mtl] = ((p_ * 2 + mtl) * 16 + l15) * 512;
    #pragma unroll
    for (int q = 0; q < 4; ++q)
      rowb[mtl][q] = bt * 64 + (p_ * 2 + mtl) * 16 + l4 * 4 + q;
  }

  float carry[2][4];
  #pragma unroll
  for (int mtl = 0; mtl < 2; ++mtl)
    #pragma unroll
    for (int q = 0; q < 4; ++q) carry[mtl][q] = 0.0f;
  if (isA) {
    int c = S + hh * 16 + l15;
    #pragma unroll
    for (int mtl = 0; mtl < 2; ++mtl)
      #pragma unroll
      for (int q = 0; q < 4; ++q) carry[mtl][q] = h0in[rowb[mtl][q] * 512 + c];
  } else if (hh == 1) {
    int c = S + l15;
    #pragma unroll
    for (int mtl = 0; mtl < 2; ++mtl)
      #pragma unroll
      for (int q = 0; q < 4; ++q) carry[mtl][q] = h1in[rowb[mtl][q] * 512 + c];
  }
  const float wout = (!isA && hh == 1) ? W_out[S + l15] : 0.0f;

  int dead = 0;   // per-wave sticky failure latch (bounded spins, no hang)

  auto st_coh = [&](unsigned short* p, unsigned long long v) {
    __hip_atomic_store((unsigned long long*)p, v, __ATOMIC_RELAXED, __HIP_MEMORY_SCOPE_AGENT);
  };
  // one parallel round-trip: 16-bit mask of FA flags >= tgt
  auto snapA16 = [&](unsigned tgt) -> unsigned {
    unsigned v = __hip_atomic_load(FAf + (l & 15) * 16, __ATOMIC_RELAXED, __HIP_MEMORY_SCOPE_AGENT);
    return (unsigned)(__ballot(v >= tgt) & 0xFFFFull);
  };
  // 16-bit chunk mask (pairs of FB flags) >= tgt
  auto snapB16 = [&](unsigned tgt) -> unsigned {
    unsigned v = __hip_atomic_load(FBf + (l & 31) * 16, __ATOMIC_RELAXED, __HIP_MEMORY_SCOPE_AGENT);
    unsigned long long bal = __ballot(v >= tgt);
    unsigned b = (unsigned)(bal & 0xFFFFFFFFull);
    unsigned m = b & (b >> 1) & 0x55555555u;
    unsigned r = 0;
    #pragma unroll
    for (int i = 0; i < 16; ++i) r |= ((m >> (2 * i)) & 1u) << i;
    return r;
  };
  auto allB = [&](unsigned tgt) -> bool {
    unsigned v = __hip_atomic_load(FBf + (l & 31) * 16, __ATOMIC_RELAXED, __HIP_MEMORY_SCOPE_AGENT);
    return __all(v >= tgt);
  };

  if (isA) {
    // ============ cell-1 blocks: compute h0(k), k = 0..TN-1 ============
    for (int k = 0; k < TN; ++k) {
      float xv[2][4];
      #pragma unroll
      for (int mtl = 0; mtl < 2; ++mtl)
        #pragma unroll
        for (int q = 0; q < 4; ++q) xv[mtl][q] = x[rowb[mtl][q] * 2048 + k];

      f32x4 acc[2][3];
      #pragma unroll
      for (int mtl = 0; mtl < 2; ++mtl)
        #pragma unroll
        for (int g = 0; g < 3; ++g) acc[mtl][g] = f32x4{0.f, 0.f, 0.f, 0.f};

      const unsigned short* srcA = h0x + ((k + 3) & 3) * 131072 + bt * 32768; // h0(k-1)

      // -------- dataflow ring: issue loads as producers publish; MFMA per quad --------
      bf16x8 fr0[16], fr1[16];
      unsigned issued = 0;
      int spins = 0;
      #pragma unroll
      for (int qd = 0; qd < 4; ++qd) {
        unsigned need = 0xFu << (qd * 4);
        while ((issued & need) != need) {
          if (dead) { issued = 0xFFFFu; break; }
          unsigned newly = snapA16((unsigned)k) & ~issued;
          if (newly) {
            #pragma unroll
            for (int j = 0; j < 16; ++j)
              if (newly & (1u << j)) {
                fr0[j] = ld_coh16(srcA + arowOff[0] + j * 32 + l4 * 8);
                fr1[j] = ld_coh16(srcA + arowOff[1] + j * 32 + l4 * 8);
              }
            issued |= newly;
          }
          if ((issued & need) != need) {
            __builtin_amdgcn_s_sleep(1);
            if (++spins > 200000) dead = 1;
          }
        }
        #pragma unroll
        for (int jj = 0; jj < 4; ++jj) {
          int ks = qd * 4 + jj;
          #pragma unroll
          for (int g = 0; g < 3; ++g) {
            bf16x8 bw = *(const bf16x8*)(wlds + (hh * 48 + g * 16 + l15) * ASTRIDE + ks * 32 + l4 * 8);
            acc[0][g] = __builtin_amdgcn_mfma_f32_16x16x32_bf16(fr0[ks], bw, acc[0][g], 0, 0, 0);
            acc[1][g] = __builtin_amdgcn_mfma_f32_16x16x32_bf16(fr1[ks], bw, acc[1][g], 0, 0, 0);
          }
        }
      }

      // -------- epilogue (R6 verbatim) --------
      int cc = hh * 16 + l15;
      int jb = hh * 48 + l15;
      float wir = fmisc[jb],       wiz = fmisc[jb + 16],       win = fmisc[jb + 32];
      float bir = fmisc[96 + jb],  biz = fmisc[96 + jb + 16],  bin = fmisc[96 + jb + 32];
      float bhr = fmisc[192 + jb], bhz = fmisc[192 + jb + 16], bhn = fmisc[192 + jb + 32];
      #pragma unroll
      for (int mtl = 0; mtl < 2; ++mtl)
        #pragma unroll
        for (int q = 0; q < 4; ++q) {
          float rg = sigf(xv[mtl][q] * wir + bir + acc[mtl][0][q] + bhr);
          float zg = sigf(xv[mtl][q] * wiz + biz + acc[mtl][1][q] + bhz);
          float ng = tanhf_(xv[mtl][q] * win + bin + rg * (acc[mtl][2][q] + bhn));
          float hv = (1.0f - zg) * ng + zg * carry[mtl][q];
          carry[mtl][q] = hv;
          sxu[((p_ * 2 + mtl) * 16 + l4 * 4 + q) * 32 + cc] = f2bf(hv);
        }
      __syncthreads();

      // -------- WAR slack: B finished tick k-4 (rarely blocks) --------
      if (k >= 4 && !dead) {
        int sp = 0;
        while (!allB((unsigned)(k - 3))) {
          __builtin_amdgcn_s_sleep(2);
          if (++sp > 200000) { dead = 1; break; }
        }
      }

      {
        const unsigned long long* sxq = (const unsigned long long*)sxu;
        unsigned long long v0 = sxq[tid * 2], v1 = sxq[tid * 2 + 1];
        unsigned short* dsth = h0x + (k & 3) * 131072
                             + (bt * 64 + (tid >> 2)) * 512 + S + (tid & 3) * 8;
        st_coh(dsth, v0);
        st_coh(dsth + 4, v1);
      }
      asm volatile("s_waitcnt vmcnt(0)" ::: "memory");
      __syncthreads();
      if (tid == 0)
        __hip_atomic_store(FAf + jA * 16, (unsigned)(k + 1),
                           __ATOMIC_RELAXED, __HIP_MEMORY_SCOPE_AGENT);
    }
  } else {
    // ============ cell-2 blocks: compute h1(j), j = 0..TN-1 ============
    for (int j = 0; j < TN; ++j) {
      f32x4 acc[2][2];
      #pragma unroll
      for (int mtl = 0; mtl < 2; ++mtl)
        #pragma unroll
        for (int g = 0; g < 2; ++g) acc[mtl][g] = f32x4{0.f, 0.f, 0.f, 0.f};

      bf16x8 fr0[16], fr1[16];
      unsigned issued;
      int spins = 0;

      // ---- half 1: h1(j-1) operand (K 512..1023); producers = B pairs, target j ----
      const unsigned short* src1 = h1x + ((j + 3) & 3) * 131072 + bt * 32768;
      issued = 0;
      #pragma unroll
      for (int qd = 0; qd < 4; ++qd) {
        unsigned need = 0xFu << (qd * 4);
        while ((issued & need) != need) {
          if (dead) { issued = 0xFFFFu; break; }
          unsigned newly = snapB16((unsigned)j) & ~issued;
          if (newly) {
            #pragma unroll
            for (int c = 0; c < 16; ++c)
              if (newly & (1u << c)) {
                fr0[c] = ld_coh16(src1 + arowOff[0] + c * 32 + l4 * 8);
                fr1[c] = ld_coh16(src1 + arowOff[1] + c * 32 + l4 * 8);
              }
            issued |= newly;
          }
          if ((issued & need) != need) {
            __builtin_amdgcn_s_sleep(1);
            if (++spins > 200000) dead = 1;
          }
        }
        #pragma unroll
        for (int jj = 0; jj < 4; ++jj) {
          int c = qd * 4 + jj;
          int ks = 16 + c;
          bf16x8 b0 = *(const bf16x8*)(wlds + (hh * 16 + l15) * B0STRIDE + ks * 32 + l4 * 8);
          acc[0][0] = __builtin_amdgcn_mfma_f32_16x16x32_bf16(fr0[c], b0, acc[0][0], 0, 0, 0);
          acc[1][0] = __builtin_amdgcn_mfma_f32_16x16x32_bf16(fr1[c], b0, acc[1][0], 0, 0, 0);
          if (hh == 1) {
            bf16x8 b1 = *(const bf16x8*)(wlds + R2BASE + l15 * BSTRIDE + c * 32 + l4 * 8);
            acc[0][1] = __builtin_amdgcn_mfma_f32_16x16x32_bf16(fr0[c], b1, acc[0][1], 0, 0, 0);
            acc[1][1] = __builtin_amdgcn_mfma_f32_16x16x32_bf16(fr1[c], b1, acc[1][1], 0, 0, 0);
          }
        }
      }

      // ---- half 2: h0(j) operand (K 0..511); producers = A blocks, target j+1 ----
      const unsigned short* src0 = h0x + (j & 3) * 131072 + bt * 32768;
      issued = 0;
      #pragma unroll
      for (int qd = 0; qd < 4; ++qd) {
        unsigned need = 0xFu << (qd * 4);
        while ((issued & need) != need) {
          if (dead) { issued = 0xFFFFu; break; }
          unsigned newly = snapA16((unsigned)(j + 1)) & ~issued;
          if (newly) {
            #pragma unroll
            for (int c = 0; c < 16; ++c)
              if (newly & (1u << c)) {
                fr0[c] = ld_coh16(src0 + arowOff[0] + c * 32 + l4 * 8);
                fr1[c] = ld_coh16(src0 + arowOff[1] + c * 32 + l4 * 8);
              }
            issued |= newly;
          }
          if ((issued & need) != need) {
            __builtin_amdgcn_s_sleep(1);
            if (++spins > 200000) dead = 1;
          }
        }
        #pragma unroll
        for (int jj = 0; jj < 4; ++jj) {
          int ks = qd * 4 + jj;
          bf16x8 b0 = *(const bf16x8*)(wlds + (hh * 16 + l15) * B0STRIDE + ks * 32 + l4 * 8);
          acc[0][0] = __builtin_amdgcn_mfma_f32_16x16x32_bf16(fr0[ks], b0, acc[0][0], 0, 0, 0);
          acc[1][0] = __builtin_amdgcn_mfma_f32_16x16x32_bf16(fr1[ks], b0, acc[1][0], 0, 0, 0);
          if (hh == 0) {
            bf16x8 b1 = *(const bf16x8*)(wlds + R1BASE + l15 * BSTRIDE + ks * 32 + l4 * 8);
            acc[0][1] = __builtin_amdgcn_mfma_f32_16x16x32_bf16(fr0[ks], b1, acc[0][1], 0, 0, 0);
            acc[1][1] = __builtin_amdgcn_mfma_f32_16x16x32_bf16(fr1[ks], b1, acc[1][1], 0, 0, 0);
          }
        }
      }

      // ---- exchange r/in_ (hh0) -> hh1 waves (R6 verbatim) ----
      if (hh == 0) {
        #pragma unroll
        for (int mtl = 0; mtl < 2; ++mtl)
          #pragma unroll
          for (int qn = 0; qn < 2; ++qn)
            #pragma unroll
            for (int q = 0; q < 4; ++q)
              exch[((p_ * 2 + qn) * 32 + mtl * 16 + l4 * 4 + q) * 17 + l15] = acc[mtl][qn][q];
      }
      __syncthreads();
      if (hh == 1) {
        float bir = fmisc[l15],      biz = fmisc[16 + l15], bin = fmisc[32 + l15];
        float bhr = fmisc[48 + l15], bhz = fmisc[64 + l15], bhn = fmisc[80 + l15];
        #pragma unroll
        for (int mtl = 0; mtl < 2; ++mtl)
          #pragma unroll
          for (int q = 0; q < 4; ++q) {
            float rv = exch[((p_ * 2 + 0) * 32 + mtl * 16 + l4 * 4 + q) * 17 + l15];
            float iv = exch[((p_ * 2 + 1) * 32 + mtl * 16 + l4 * 4 + q) * 17 + l15];
            float rg = sigf(rv + bir + bhr);
            float zg = sigf(acc[mtl][0][q] + biz + bhz);
            float ng = tanhf_(iv + bin + rg * (acc[mtl][1][q] + bhn));
            float hv = (1.0f - zg) * ng + zg * carry[mtl][q];
            carry[mtl][q] = hv;
            sxu[((p_ * 2 + mtl) * 16 + l4 * 4 + q) * 16 + l15] = f2bf(hv);
            if (j == TN - 1) atomicAdd(&out[rowb[mtl][q]], hv * wout);
          }
      }
      __syncthreads();
      {
        const unsigned long long* sxq = (const unsigned long long*)sxu;
        unsigned long long v = sxq[tid];
        unsigned short* dsth = h1x + (j & 3) * 131072
                             + (bt * 64 + (tid >> 2)) * 512 + S + (tid & 3) * 4;
        st_coh(dsth, v);
      }
      asm volatile("s_waitcnt vmcnt(0)" ::: "memory");
      __syncthreads();
      if (tid == 0)
        __hip_atomic_store(FBf + jB * 16, (unsigned)(j + 1),
                           __ATOMIC_RELAXED, __HIP_MEMORY_SCOPE_AGENT);
    }
  }
}

extern "C" void kernel_launch(void* const* d_in, const int* in_sizes, int n_in,
                              void* d_out, int out_size, void* d_ws, size_t ws_size,
                              hipStream_t stream) {
  const float* x     = (const float*)d_in[0];
  const float* h0in  = (const float*)d_in[1];
  const float* h1in  = (const float*)d_in[2];
  const float* W_ih1 = (const float*)d_in[3];
  const float* W_hh1 = (const float*)d_in[4];
  const float* b_ih1 = (const float*)d_in[5];
  const float* b_hh1 = (const float*)d_in[6];
  const float* W_ih2 = (const float*)d_in[7];
  const float* W_hh2 = (const float*)d_in[8];
  const float* b_ih2 = (const float*)d_in[9];
  const float* b_hh2 = (const float*)d_in[10];
  const float* W_out = (const float*)d_in[11];
  const float* b_out = (const float*)d_in[12];
  float* out = (float*)d_out;
  char* ws = (char*)d_ws;

  (void)in_sizes; (void)n_in; (void)out_size; (void)ws_size;

  hipFuncSetAttribute((const void*)gru_main,
                      hipFuncAttributeMaxDynamicSharedMemorySize, SMEM_BYTES);

  hipLaunchKernelGGL(gru_init, dim3(512), dim3(256), 0, stream,
                     h0in, h1in, b_out, out, ws);

  void* args[] = { (void*)&x,
                   (void*)&W_ih1, (void*)&W_hh1, (void*)&b_ih1, (void*)&b_hh1,
                   (void*)&W_ih2, (void*)&W_hh2, (void*)&b_ih2, (void*)&b_hh2,
                   (void*)&W_out, (void*)&b_out,
                   (void*)&h0in, (void*)&h1in,
                   (void*)&out, (void*)&ws };
  hipLaunchCooperativeKernel((const void*)gru_main, dim3(NBLK), dim3(256),
                             args, SMEM_BYTES, stream);
}

// Round 13
// 38588.498 us; speedup vs baseline: 1.2970x; 1.1245x over previous
//
#include <hip/hip_runtime.h>
#include <stdint.h>

// ---------------- problem constants ----------------
#define TN     2048     // time steps
#define NBLK   192      // 4 groups x (16 A-blocks + 32 B-blocks)  [R6 structure]

// LDS layout (pad strides == 6 mod 32 words -> ~2-way bank aliasing, free):
#define ASTRIDE  524
#define B0STRIDE 1036
#define BSTRIDE  524
#define R1BASE   33152          // 32*1036
#define R2BASE   41536          // R1BASE + 16*524
#define EXCH_OFF  100608
#define SX_OFF    109312
#define FMISC_OFF 113408
#define SMEM_BYTES 114688

// ws layout:
//   0       : h0x bf16 [4 slots][256][512]   (1 MiB)   slot(t)=t&3; t=-1 -> slot 3
//   1048576 : h1x bf16 [4 slots][256][512]   (1 MiB)
//   2097152 : counters; group g at +g*256 bytes: u32 pA (+0), u32 pB (+4)
#define H0_OFF  0
#define H1_OFF  1048576
#define CNT_OFF 2097152

typedef __attribute__((ext_vector_type(8))) short bf16x8;
typedef __attribute__((ext_vector_type(4))) float f32x4;
typedef __attribute__((ext_vector_type(4))) int   i32x4;

__device__ __forceinline__ float sigf(float v)   { return 1.0f / (1.0f + __expf(-v)); }
__device__ __forceinline__ float tanhf_(float v) { return 2.0f / (1.0f + __expf(-2.0f * v)) - 1.0f; }
__device__ __forceinline__ unsigned short f2bf(float f) {
  unsigned u = __float_as_uint(f);
  u += 0x7fffu + ((u >> 16) & 1u);   // RNE
  return (unsigned short)(u >> 16);
}

// Agent-scope (IF coherence point) 16B fragment load -- proven R6/R7/R10-R12.
__device__ __forceinline__ bf16x8 ld_coh16(const unsigned short* p) {
  union { unsigned long long q[2]; bf16x8 v; } u;
  u.q[0] = __hip_atomic_load((const unsigned long long*)p,
                             __ATOMIC_RELAXED, __HIP_MEMORY_SCOPE_AGENT);
  u.q[1] = __hip_atomic_load((const unsigned long long*)p + 1,
                             __ATOMIC_RELAXED, __HIP_MEMORY_SCOPE_AGENT);
  return u.v;
}

// Re-run safe init: state mirrors (slot 3), out = b_out, counters = 0.
extern "C" __global__ void gru_init(const float* __restrict__ h0,
                                    const float* __restrict__ h1,
                                    const float* __restrict__ b_out,
                                    float* __restrict__ out,
                                    char* __restrict__ ws) {
  int i = blockIdx.x * 256 + threadIdx.x;     // 512 blocks
  unsigned short* h0x = (unsigned short*)(ws + H0_OFF);
  unsigned short* h1x = (unsigned short*)(ws + H1_OFF);
  h0x[3 * 131072 + i] = f2bf(h0[i]);
  h1x[3 * 131072 + i] = f2bf(h1[i]);
  if (blockIdx.x == 0) out[threadIdx.x] = b_out[0];
  if (blockIdx.x == 1) ((unsigned*)(ws + CNT_OFF))[threadIdx.x] = 0u;  // covers 4*256B
}

extern "C" __global__ void __launch_bounds__(256, 1)
gru_main(const float* __restrict__ x,
         const float* __restrict__ W_ih1, const float* __restrict__ W_hh1,
         const float* __restrict__ b_ih1, const float* __restrict__ b_hh1,
         const float* __restrict__ W_ih2, const float* __restrict__ W_hh2,
         const float* __restrict__ b_ih2, const float* __restrict__ b_hh2,
         const float* __restrict__ W_out, const float* __restrict__ b_out,
         const float* __restrict__ h0in, const float* __restrict__ h1in,
         float* __restrict__ out, char* __restrict__ ws)
{
  extern __shared__ char smem[];
  unsigned short* wlds = (unsigned short*)smem;
  float* exch  = (float*)(smem + EXCH_OFF);
  unsigned short* sxu = (unsigned short*)(smem + SX_OFF);
  float* fmisc = (float*)(smem + FMISC_OFF);

  unsigned short* h0x = (unsigned short*)(ws + H0_OFF);
  unsigned short* h1x = (unsigned short*)(ws + H1_OFF);

  const int bid = blockIdx.x, tid = threadIdx.x;
  const int w = tid >> 6, l = tid & 63, l15 = l & 15, l4 = l >> 4;
  const int p_ = w >> 1;     // M half: rows 0-31 / 32-63
  const int hh = w & 1;      // A: column half; B: gate role

  // group mapping, XCD-aware (R6-proven)
  const int bt  = (bid & 7) >> 1;
  const int sub = (bid >> 3) * 2 + (bid & 1);
  const bool isA = (sub < 16);
  const int S = isA ? sub * 32 : (sub - 16) * 16;

  unsigned* cnt = (unsigned*)(ws + CNT_OFF + bt * 256);   // pA at +0, pB at +4

  // ---------------- weight preload into LDS (bf16)  [R6 verbatim] ----------------
  if (isA) {
    for (int idx = tid; idx < 96 * 512; idx += 256) {
      int j = idx >> 9, kk = idx & 511;
      int h = j / 48, rr = j % 48, g = rr >> 4, c2 = rr & 15;
      int grow = g * 512 + S + h * 16 + c2;
      wlds[j * ASTRIDE + kk] = f2bf(W_hh1[grow * 512 + kk]);
    }
    if (tid < 96) {
      int j = tid, h = j / 48, rr = j % 48, g = rr >> 4, c2 = rr & 15;
      int grow = g * 512 + S + h * 16 + c2;
      fmisc[j]       = W_ih1[grow];
      fmisc[96 + j]  = b_ih1[grow];
      fmisc[192 + j] = b_hh1[grow];
    }
  } else {
    for (int idx = tid; idx < 32 * 1024; idx += 256) {
      int j = idx >> 10, kk = idx & 1023;
      int g = j >> 4, c2 = S + (j & 15);
      float v = (kk < 512) ? W_ih2[(g * 512 + c2) * 512 + kk]
                           : W_hh2[(g * 512 + c2) * 512 + kk - 512];
      wlds[j * B0STRIDE + kk] = f2bf(v);
    }
    for (int idx = tid; idx < 16 * 512; idx += 256) {
      int j2 = idx >> 9, kk = idx & 511;
      wlds[R1BASE + j2 * BSTRIDE + kk] = f2bf(W_ih2[(1024 + S + j2) * 512 + kk]);
      wlds[R2BASE + j2 * BSTRIDE + kk] = f2bf(W_hh2[(1024 + S + j2) * 512 + kk]);
    }
    if (tid < 48) {
      int g = tid >> 4, c2 = S + (tid & 15);
      fmisc[tid]      = b_ih2[g * 512 + c2];
      fmisc[48 + tid] = b_hh2[g * 512 + c2];
    }
  }
  __syncthreads();

  // ---------------- per-thread constants / carries  [R6 verbatim] ----------------
  int rowb[2][4];
  int arowOff[2];
  #pragma unroll
  for (int mtl = 0; mtl < 2; ++mtl) {
    arowOff[mtl] = ((p_ * 2 + mtl) * 16 + l15) * 512;
    #pragma unroll
    for (int q = 0; q < 4; ++q)
      rowb[mtl][q] = bt * 64 + (p_ * 2 + mtl) * 16 + l4 * 4 + q;
  }

  float carry[2][4];
  #pragma unroll
  for (int mtl = 0; mtl < 2; ++mtl)
    #pragma unroll
    for (int q = 0; q < 4; ++q) carry[mtl][q] = 0.0f;
  if (isA) {
    int c = S + hh * 16 + l15;
    #pragma unroll
    for (int mtl = 0; mtl < 2; ++mtl)
      #pragma unroll
      for (int q = 0; q < 4; ++q) carry[mtl][q] = h0in[rowb[mtl][q] * 512 + c];
  } else if (hh == 1) {
    int c = S + l15;
    #pragma unroll
    for (int mtl = 0; mtl < 2; ++mtl)
      #pragma unroll
      for (int q = 0; q < 4; ++q) carry[mtl][q] = h1in[rowb[mtl][q] * 512 + c];
  }
  const float wout = (!isA && hh == 1) ? W_out[S + l15] : 0.0f;

  int dead = 0;   // per-wave latch; wave-uniform (all lanes load same address)

  auto st_coh = [&](unsigned short* p, unsigned long long v) {
    __hip_atomic_store((unsigned long long*)p, v, __ATOMIC_RELAXED, __HIP_MEMORY_SCOPE_AGENT);
  };
  // all-wave pure-spin wait: every wave loads both counters in one u64, no sleep
  auto ldcnt = [&]() -> unsigned long long {
    return __hip_atomic_load((const unsigned long long*)cnt,
                             __ATOMIC_RELAXED, __HIP_MEMORY_SCOPE_AGENT);
  };
  auto wave_wait = [&](unsigned tA, unsigned tB) {
    if (dead) return;
    int spins = 0;
    for (;;) {
      unsigned long long v = ldcnt();
      if ((unsigned)(v & 0xffffffffu) >= tA && (unsigned)(v >> 32) >= tB) break;
      if (++spins > 400000) { dead = 1; break; }   // bounded failure, no hang
    }
  };

  if (isA) {
    // ============ cell-1 blocks: compute h0(k), k = 0..TN-1 ============
    for (int k = 0; k < TN; ++k) {
      float xv[2][4];
      #pragma unroll
      for (int mtl = 0; mtl < 2; ++mtl)
        #pragma unroll
        for (int q = 0; q < 4; ++q) xv[mtl][q] = x[rowb[mtl][q] * 2048 + k];

      // wait: peers' h0(k-1) published; WAR slack vs B (4-slot ring)
      wave_wait(16u * (unsigned)k, (k >= 3) ? 32u * (unsigned)(k - 3) : 0u);

      f32x4 acc[2][3];
      #pragma unroll
      for (int mtl = 0; mtl < 2; ++mtl)
        #pragma unroll
        for (int g = 0; g < 3; ++g) acc[mtl][g] = f32x4{0.f, 0.f, 0.f, 0.f};

      const unsigned short* srcA = h0x + ((k + 3) & 3) * 131072 + bt * 32768; // h0(k-1)
      #pragma unroll 4
      for (int ks = 0; ks < 16; ++ks) {
        bf16x8 af[2];
        #pragma unroll
        for (int mtl = 0; mtl < 2; ++mtl)
          af[mtl] = ld_coh16(srcA + arowOff[mtl] + ks * 32 + l4 * 8);
        #pragma unroll
        for (int g = 0; g < 3; ++g) {
          bf16x8 bw = *(const bf16x8*)(wlds + (hh * 48 + g * 16 + l15) * ASTRIDE + ks * 32 + l4 * 8);
          #pragma unroll
          for (int mtl = 0; mtl < 2; ++mtl)
            acc[mtl][g] = __builtin_amdgcn_mfma_f32_16x16x32_bf16(af[mtl], bw, acc[mtl][g], 0, 0, 0);
        }
      }

      int cc = hh * 16 + l15;          // local column 0..31
      int jb = hh * 48 + l15;
      float wir = fmisc[jb],       wiz = fmisc[jb + 16],       win = fmisc[jb + 32];
      float bir = fmisc[96 + jb],  biz = fmisc[96 + jb + 16],  bin = fmisc[96 + jb + 32];
      float bhr = fmisc[192 + jb], bhz = fmisc[192 + jb + 16], bhn = fmisc[192 + jb + 32];
      #pragma unroll
      for (int mtl = 0; mtl < 2; ++mtl)
        #pragma unroll
        for (int q = 0; q < 4; ++q) {
          float rg = sigf(xv[mtl][q] * wir + bir + acc[mtl][0][q] + bhr);
          float zg = sigf(xv[mtl][q] * wiz + biz + acc[mtl][1][q] + bhz);
          float ng = tanhf_(xv[mtl][q] * win + bin + rg * (acc[mtl][2][q] + bhn));
          float hv = (1.0f - zg) * ng + zg * carry[mtl][q];
          carry[mtl][q] = hv;
          sxu[((p_ * 2 + mtl) * 16 + l4 * 4 + q) * 32 + cc] = f2bf(hv);  // repack
        }
      __syncthreads();
      {
        // one 16B write-through store per thread (halves drain population vs 2x8B)
        i32x4 v = ((const i32x4*)sxu)[tid];
        unsigned short* dsth = h0x + (k & 3) * 131072
                             + (bt * 64 + (tid >> 2)) * 512 + S + (tid & 3) * 8;
        asm volatile("global_store_dwordx4 %0, %1, off sc1"
                     :: "v"(dsth), "v"(v) : "memory");
      }
      asm volatile("s_waitcnt vmcnt(0)" ::: "memory");
      __syncthreads();
      if (tid == 0)
        __hip_atomic_fetch_add(cnt, 1u, __ATOMIC_RELAXED, __HIP_MEMORY_SCOPE_AGENT);  // pA
    }
  } else {
    // ============ cell-2 blocks: compute h1(j), j = 0..TN-1 ============
    for (int j = 0; j < TN; ++j) {
      f32x4 acc[2][2];
      #pragma unroll
      for (int mtl = 0; mtl < 2; ++mtl)
        #pragma unroll
        for (int g = 0; g < 2; ++g) acc[mtl][g] = f32x4{0.f, 0.f, 0.f, 0.f};

      // ---- phase 1: h1(j-1) half (K 512..1023) -- needs pB >= 32j ----
      wave_wait(0u, 32u * (unsigned)j);

      const unsigned short* src1 = h1x + ((j + 3) & 3) * 131072 + bt * 32768; // h1(j-1)
      #pragma unroll 4
      for (int ks = 16; ks < 32; ++ks) {
        int koff = (ks & 15) * 32;
        bf16x8 af[2];
        #pragma unroll
        for (int mtl = 0; mtl < 2; ++mtl)
          af[mtl] = ld_coh16(src1 + arowOff[mtl] + koff + l4 * 8);
        bf16x8 b0 = *(const bf16x8*)(wlds + (hh * 16 + l15) * B0STRIDE + ks * 32 + l4 * 8);
        #pragma unroll
        for (int mtl = 0; mtl < 2; ++mtl)
          acc[mtl][0] = __builtin_amdgcn_mfma_f32_16x16x32_bf16(af[mtl], b0, acc[mtl][0], 0, 0, 0);
        if (hh == 1) {
          bf16x8 b1 = *(const bf16x8*)(wlds + R2BASE + l15 * BSTRIDE + (ks - 16) * 32 + l4 * 8);
          #pragma unroll
          for (int mtl = 0; mtl < 2; ++mtl)
            acc[mtl][1] = __builtin_amdgcn_mfma_f32_16x16x32_bf16(af[mtl], b1, acc[mtl][1], 0, 0, 0);
        }
      }

      // ---- phase 2: h0(j) half (K 0..511) -- needs pA >= 16(j+1) ----
      wave_wait(16u * (unsigned)(j + 1), 0u);

      const unsigned short* src0 = h0x + (j & 3) * 131072 + bt * 32768;       // h0(j)
      #pragma unroll 4
      for (int ks = 0; ks < 16; ++ks) {
        bf16x8 af[2];
        #pragma unroll
        for (int mtl = 0; mtl < 2; ++mtl)
          af[mtl] = ld_coh16(src0 + arowOff[mtl] + ks * 32 + l4 * 8);
        bf16x8 b0 = *(const bf16x8*)(wlds + (hh * 16 + l15) * B0STRIDE + ks * 32 + l4 * 8);
        #pragma unroll
        for (int mtl = 0; mtl < 2; ++mtl)
          acc[mtl][0] = __builtin_amdgcn_mfma_f32_16x16x32_bf16(af[mtl], b0, acc[mtl][0], 0, 0, 0);
        if (hh == 0) {
          bf16x8 b1 = *(const bf16x8*)(wlds + R1BASE + l15 * BSTRIDE + ks * 32 + l4 * 8);
          #pragma unroll
          for (int mtl = 0; mtl < 2; ++mtl)
            acc[mtl][1] = __builtin_amdgcn_mfma_f32_16x16x32_bf16(af[mtl], b1, acc[mtl][1], 0, 0, 0);
        }
      }

      // exchange r/in_ (hh0) -> hh1 waves
      if (hh == 0) {
        #pragma unroll
        for (int mtl = 0; mtl < 2; ++mtl)
          #pragma unroll
          for (int qn = 0; qn < 2; ++qn)
            #pragma unroll
            for (int q = 0; q < 4; ++q)
              exch[((p_ * 2 + qn) * 32 + mtl * 16 + l4 * 4 + q) * 17 + l15] = acc[mtl][qn][q];
      }
      __syncthreads();
      if (hh == 1) {
        float bir = fmisc[l15],      biz = fmisc[16 + l15], bin = fmisc[32 + l15];
        float bhr = fmisc[48 + l15], bhz = fmisc[64 + l15], bhn = fmisc[80 + l15];
        #pragma unroll
        for (int mtl = 0; mtl < 2; ++mtl)
          #pragma unroll
          for (int q = 0; q < 4; ++q) {
            float rv = exch[((p_ * 2 + 0) * 32 + mtl * 16 + l4 * 4 + q) * 17 + l15];
            float iv = exch[((p_ * 2 + 1) * 32 + mtl * 16 + l4 * 4 + q) * 17 + l15];
            float rg = sigf(rv + bir + bhr);
            float zg = sigf(acc[mtl][0][q] + biz + bhz);
            float ng = tanhf_(iv + bin + rg * (acc[mtl][1][q] + bhn));
            float hv = (1.0f - zg) * ng + zg * carry[mtl][q];
            carry[mtl][q] = hv;
            sxu[((p_ * 2 + mtl) * 16 + l4 * 4 + q) * 16 + l15] = f2bf(hv);  // repack
            if (j == TN - 1) atomicAdd(&out[rowb[mtl][q]], hv * wout);      // projection
          }
      }
      __syncthreads();
      {
        const unsigned long long* sxq = (const unsigned long long*)sxu;
        unsigned long long v = sxq[tid];
        unsigned short* dsth = h1x + (j & 3) * 131072
                             + (bt * 64 + (tid >> 2)) * 512 + S + (tid & 3) * 4;
        st_coh(dsth, v);
      }
      asm volatile("s_waitcnt vmcnt(0)" ::: "memory");
      __syncthreads();
      if (tid == 0)
        __hip_atomic_fetch_add(cnt + 1, 1u, __ATOMIC_RELAXED, __HIP_MEMORY_SCOPE_AGENT); // pB
    }
  }
}

extern "C" void kernel_launch(void* const* d_in, const int* in_sizes, int n_in,
                              void* d_out, int out_size, void* d_ws, size_t ws_size,
                              hipStream_t stream) {
  const float* x     = (const float*)d_in[0];
  const float* h0in  = (const float*)d_in[1];
  const float* h1in  = (const float*)d_in[2];
  const float* W_ih1 = (const float*)d_in[3];
  const float* W_hh1 = (const float*)d_in[4];
  const float* b_ih1 = (const float*)d_in[5];
  const float* b_hh1 = (const float*)d_in[6];
  const float* W_ih2 = (const float*)d_in[7];
  const float* W_hh2 = (const float*)d_in[8];
  const float* b_ih2 = (const float*)d_in[9];
  const float* b_hh2 = (const float*)d_in[10];
  const float* W_out = (const float*)d_in[11];
  const float* b_out = (const float*)d_in[12];
  float* out = (float*)d_out;
  char* ws = (char*)d_ws;

  (void)in_sizes; (void)n_in; (void)out_size; (void)ws_size;

  hipFuncSetAttribute((const void*)gru_main,
                      hipFuncAttributeMaxDynamicSharedMemorySize, SMEM_BYTES);

  hipLaunchKernelGGL(gru_init, dim3(512), dim3(256), 0, stream,
                     h0in, h1in, b_out, out, ws);

  void* args[] = { (void*)&x,
                   (void*)&W_ih1, (void*)&W_hh1, (void*)&b_ih1, (void*)&b_hh1,
                   (void*)&W_ih2, (void*)&W_hh2, (void*)&b_ih2, (void*)&b_hh2,
                   (void*)&W_out, (void*)&b_out,
                   (void*)&h0in, (void*)&h1in,
                   (void*)&out, (void*)&ws };
  hipLaunchCooperativeKernel((const void*)gru_main, dim3(NBLK), dim3(256),
                             args, SMEM_BYTES, stream);
}

// Round 14
// 36952.219 us; speedup vs baseline: 1.3544x; 1.0443x over previous
//
#include <hip/hip_runtime.h>
#include <stdint.h>

// ---------------- problem constants ----------------
#define TN     2048     // time steps
#define NBLK   192      // 4 groups x (16 A-blocks + 32 B-blocks)

// LDS layout (pad strides == 6 mod 32 words -> ~2-way bank aliasing, free):
#define ASTRIDE  524
#define B0STRIDE 1036
#define BSTRIDE  524
#define R1BASE   33152          // 32*1036
#define R2BASE   41536          // R1BASE + 16*524
#define EXCH_OFF  100608
#define SX_OFF    109312
#define FMISC_OFF 113408
#define SMEM_BYTES 114688

// ws layout:
//   0       : h0x bf16 [4 slots][256][512]   (1 MiB)   slot(t)=t&3; t=-1 -> slot 3
//   1048576 : h1x bf16 [4 slots][256][512]   (1 MiB)
//   2097152 : counters u32[256]; group g: prodA at g*64, prodB at g*64+32
#define H0_OFF  0
#define H1_OFF  1048576
#define CNT_OFF 2097152

typedef __attribute__((ext_vector_type(8))) short bf16x8;
typedef __attribute__((ext_vector_type(4))) float f32x4;

__device__ __forceinline__ float sigf(float v)   { return 1.0f / (1.0f + __expf(-v)); }
__device__ __forceinline__ float tanhf_(float v) { return 2.0f / (1.0f + __expf(-2.0f * v)) - 1.0f; }
__device__ __forceinline__ unsigned short f2bf(float f) {
  unsigned u = __float_as_uint(f);
  u += 0x7fffu + ((u >> 16) & 1u);   // RNE
  return (unsigned short)(u >> 16);
}

// L2-bypassing (agent-scope, sc1) 16B fragment load from the IF coherence
// point -- no cache-maintenance op needed to observe remote writes.
__device__ __forceinline__ bf16x8 ld_coh16(const unsigned short* p) {
  union { unsigned long long q[2]; bf16x8 v; } u;
  u.q[0] = __hip_atomic_load((const unsigned long long*)p,
                             __ATOMIC_RELAXED, __HIP_MEMORY_SCOPE_AGENT);
  u.q[1] = __hip_atomic_load((const unsigned long long*)p + 1,
                             __ATOMIC_RELAXED, __HIP_MEMORY_SCOPE_AGENT);
  return u.v;
}

// Re-run safe init: state mirrors (slot 3), out = b_out, counters = 0.
extern "C" __global__ void gru_init(const float* __restrict__ h0,
                                    const float* __restrict__ h1,
                                    const float* __restrict__ b_out,
                                    float* __restrict__ out,
                                    char* __restrict__ ws) {
  int i = blockIdx.x * 256 + threadIdx.x;     // 512 blocks
  unsigned short* h0x = (unsigned short*)(ws + H0_OFF);
  unsigned short* h1x = (unsigned short*)(ws + H1_OFF);
  h0x[3 * 131072 + i] = f2bf(h0[i]);
  h1x[3 * 131072 + i] = f2bf(h1[i]);
  if (blockIdx.x == 0) out[threadIdx.x] = b_out[0];
  if (blockIdx.x == 1) ((unsigned*)(ws + CNT_OFF))[threadIdx.x] = 0u;
}

extern "C" __global__ void __launch_bounds__(256, 1)
gru_main(const float* __restrict__ x,
         const float* __restrict__ W_ih1, const float* __restrict__ W_hh1,
         const float* __restrict__ b_ih1, const float* __restrict__ b_hh1,
         const float* __restrict__ W_ih2, const float* __restrict__ W_hh2,
         const float* __restrict__ b_ih2, const float* __restrict__ b_hh2,
         const float* __restrict__ W_out, const float* __restrict__ b_out,
         const float* __restrict__ h0in, const float* __restrict__ h1in,
         float* __restrict__ out, char* __restrict__ ws)
{
  extern __shared__ char smem[];
  unsigned short* wlds = (unsigned short*)smem;
  float* exch  = (float*)(smem + EXCH_OFF);
  unsigned short* sxu = (unsigned short*)(smem + SX_OFF);
  float* fmisc = (float*)(smem + FMISC_OFF);

  unsigned short* h0x = (unsigned short*)(ws + H0_OFF);
  unsigned short* h1x = (unsigned short*)(ws + H1_OFF);

  const int bid = blockIdx.x, tid = threadIdx.x;
  const int w = tid >> 6, l = tid & 63, l15 = l & 15, l4 = l >> 4;
  const int p_ = w >> 1;     // M half: rows 0-31 / 32-63 of the 64-row batch tile
  const int hh = w & 1;      // A: column half; B: gate role (r,in_ / z,hn)

  // group mapping, XCD-aware: blocks bid%8 in {2g,2g+1} form group g
  const int bt  = (bid & 7) >> 1;                 // group = batch tile
  const int sub = (bid >> 3) * 2 + (bid & 1);     // 0..47 within group
  const bool isA = (sub < 16);
  const int S = isA ? sub * 32 : (sub - 16) * 16;

  unsigned* pA = (unsigned*)(ws + CNT_OFF) + bt * 64;
  unsigned* pB = pA + 32;

  // ---------------- weight preload into LDS (bf16) ----------------
  if (isA) {
    for (int idx = tid; idx < 96 * 512; idx += 256) {
      int j = idx >> 9, kk = idx & 511;
      int h = j / 48, rr = j % 48, g = rr >> 4, c2 = rr & 15;
      int grow = g * 512 + S + h * 16 + c2;
      wlds[j * ASTRIDE + kk] = f2bf(W_hh1[grow * 512 + kk]);
    }
    if (tid < 96) {
      int j = tid, h = j / 48, rr = j % 48, g = rr >> 4, c2 = rr & 15;
      int grow = g * 512 + S + h * 16 + c2;
      fmisc[j]       = W_ih1[grow];
      fmisc[96 + j]  = b_ih1[grow];
      fmisc[192 + j] = b_hh1[grow];
    }
  } else {
    // region0: rows 0..15 = r-gate, 16..31 = z-gate; K=1024 = [W_ih2 | W_hh2]
    for (int idx = tid; idx < 32 * 1024; idx += 256) {
      int j = idx >> 10, kk = idx & 1023;
      int g = j >> 4, c2 = S + (j & 15);
      float v = (kk < 512) ? W_ih2[(g * 512 + c2) * 512 + kk]
                           : W_hh2[(g * 512 + c2) * 512 + kk - 512];
      wlds[j * B0STRIDE + kk] = f2bf(v);
    }
    // region1: in_ rows (W_ih2 n-gate); region2: hn rows (W_hh2 n-gate); K=512
    for (int idx = tid; idx < 16 * 512; idx += 256) {
      int j2 = idx >> 9, kk = idx & 511;
      wlds[R1BASE + j2 * BSTRIDE + kk] = f2bf(W_ih2[(1024 + S + j2) * 512 + kk]);
      wlds[R2BASE + j2 * BSTRIDE + kk] = f2bf(W_hh2[(1024 + S + j2) * 512 + kk]);
    }
    if (tid < 48) {
      int g = tid >> 4, c2 = S + (tid & 15);
      fmisc[tid]      = b_ih2[g * 512 + c2];
      fmisc[48 + tid] = b_hh2[g * 512 + c2];
    }
  }
  __syncthreads();

  // ---------------- per-thread constants / carries ----------------
  int rowb[2][4];
  int arowOff[2];
  #pragma unroll
  for (int mtl = 0; mtl < 2; ++mtl) {
    arowOff[mtl] = ((p_ * 2 + mtl) * 16 + l15) * 512;     // A-fragment row (lane&15-based)
    #pragma unroll
    for (int q = 0; q < 4; ++q)
      rowb[mtl][q] = bt * 64 + (p_ * 2 + mtl) * 16 + l4 * 4 + q;  // D row (reg-based)
  }

  float carry[2][4];
  #pragma unroll
  for (int mtl = 0; mtl < 2; ++mtl)
    #pragma unroll
    for (int q = 0; q < 4; ++q) carry[mtl][q] = 0.0f;
  if (isA) {
    int c = S + hh * 16 + l15;
    #pragma unroll
    for (int mtl = 0; mtl < 2; ++mtl)
      #pragma unroll
      for (int q = 0; q < 4; ++q) carry[mtl][q] = h0in[rowb[mtl][q] * 512 + c];
  } else if (hh == 1) {
    int c = S + l15;
    #pragma unroll
    for (int mtl = 0; mtl < 2; ++mtl)
      #pragma unroll
      for (int q = 0; q < 4; ++q) carry[mtl][q] = h1in[rowb[mtl][q] * 512 + c];
  }
  const float wout = (!isA && hh == 1) ? W_out[S + l15] : 0.0f;

  int dead = 0;   // only tid0's copy matters

  // wait until *c0 >= t0 && *c1 >= t1 (tid0 polls relaxed/sc1).
  // BACKOFF polling: one immediate fast-path check, then ~1.5K-cycle sleeps.
  // A 48-block read storm at <=256cy spacing saturates the counter line's home
  // bank and delays the producer's own update; 0.7us spacing keeps it cold.
  auto block_wait = [&](unsigned* c0, unsigned t0, unsigned* c1, unsigned t1) {
    if (tid == 0 && !dead) {
      if (__hip_atomic_load(c0, __ATOMIC_RELAXED, __HIP_MEMORY_SCOPE_AGENT) < t0 ||
          __hip_atomic_load(c1, __ATOMIC_RELAXED, __HIP_MEMORY_SCOPE_AGENT) < t1) {
        int spins = 0;
        for (;;) {
          __builtin_amdgcn_s_sleep(24);   // backoff FIRST, then re-check
          if (__hip_atomic_load(c0, __ATOMIC_RELAXED, __HIP_MEMORY_SCOPE_AGENT) >= t0 &&
              __hip_atomic_load(c1, __ATOMIC_RELAXED, __HIP_MEMORY_SCOPE_AGENT) >= t1) break;
          if (++spins > 30000) { dead = 1; break; }   // bounded failure, no hang
        }
      }
    }
    __syncthreads();
  };
  // publisher: all state stores are sc1 write-through; drain them, then relaxed add
  auto block_publish = [&](unsigned* c) {
    asm volatile("s_waitcnt vmcnt(0)" ::: "memory");
    __syncthreads();
    if (tid == 0) __hip_atomic_fetch_add(c, 1u, __ATOMIC_RELAXED, __HIP_MEMORY_SCOPE_AGENT);
  };
  // coherent (IF-level, sc1) u64 store of repacked state
  auto st_coh = [&](unsigned short* p, unsigned long long v) {
    __hip_atomic_store((unsigned long long*)p, v, __ATOMIC_RELAXED, __HIP_MEMORY_SCOPE_AGENT);
  };

  if (isA) {
    // ============ cell-1 blocks: compute h0(k), k = 0..TN-1 ============
    for (int k = 0; k < TN; ++k) {
      // x column loads are flag-independent: issue before the wait
      float xv[2][4];
      #pragma unroll
      for (int mtl = 0; mtl < 2; ++mtl)
        #pragma unroll
        for (int q = 0; q < 4; ++q) xv[mtl][q] = x[rowb[mtl][q] * 2048 + k];

      block_wait(pA, 16u * (unsigned)k,
                 pB, (k >= 3) ? 32u * (unsigned)(k - 3) : 0u);

      f32x4 acc[2][3];
      #pragma unroll
      for (int mtl = 0; mtl < 2; ++mtl)
        #pragma unroll
        for (int g = 0; g < 3; ++g) acc[mtl][g] = f32x4{0.f, 0.f, 0.f, 0.f};

      const unsigned short* srcA = h0x + ((k + 3) & 3) * 131072 + bt * 32768; // h0(k-1)
      #pragma unroll 4
      for (int ks = 0; ks < 16; ++ks) {
        bf16x8 af[2];
        #pragma unroll
        for (int mtl = 0; mtl < 2; ++mtl)
          af[mtl] = ld_coh16(srcA + arowOff[mtl] + ks * 32 + l4 * 8);
        #pragma unroll
        for (int g = 0; g < 3; ++g) {
          bf16x8 bw = *(const bf16x8*)(wlds + (hh * 48 + g * 16 + l15) * ASTRIDE + ks * 32 + l4 * 8);
          #pragma unroll
          for (int mtl = 0; mtl < 2; ++mtl)
            acc[mtl][g] = __builtin_amdgcn_mfma_f32_16x16x32_bf16(af[mtl], bw, acc[mtl][g], 0, 0, 0);
        }
      }

      int cc = hh * 16 + l15;          // local column 0..31
      int jb = hh * 48 + l15;
      float wir = fmisc[jb],       wiz = fmisc[jb + 16],       win = fmisc[jb + 32];
      float bir = fmisc[96 + jb],  biz = fmisc[96 + jb + 16],  bin = fmisc[96 + jb + 32];
      float bhr = fmisc[192 + jb], bhz = fmisc[192 + jb + 16], bhn = fmisc[192 + jb + 32];
      #pragma unroll
      for (int mtl = 0; mtl < 2; ++mtl)
        #pragma unroll
        for (int q = 0; q < 4; ++q) {
          float rg = sigf(xv[mtl][q] * wir + bir + acc[mtl][0][q] + bhr);
          float zg = sigf(xv[mtl][q] * wiz + biz + acc[mtl][1][q] + bhz);
          float ng = tanhf_(xv[mtl][q] * win + bin + rg * (acc[mtl][2][q] + bhn));
          float hv = (1.0f - zg) * ng + zg * carry[mtl][q];
          carry[mtl][q] = hv;
          sxu[((p_ * 2 + mtl) * 16 + l4 * 4 + q) * 32 + cc] = f2bf(hv);  // repack
        }
      __syncthreads();
      {
        const unsigned long long* sxq = (const unsigned long long*)sxu;
        unsigned long long v0 = sxq[tid * 2], v1 = sxq[tid * 2 + 1];
        unsigned short* dsth = h0x + (k & 3) * 131072
                             + (bt * 64 + (tid >> 2)) * 512 + S + (tid & 3) * 8;
        st_coh(dsth, v0);
        st_coh(dsth + 4, v1);
      }
      block_publish(pA);
    }
  } else {
    // ============ cell-2 blocks: compute h1(j), j = 0..TN-1 ============
    for (int j = 0; j < TN; ++j) {
      f32x4 acc[2][2];
      #pragma unroll
      for (int mtl = 0; mtl < 2; ++mtl)
        #pragma unroll
        for (int g = 0; g < 2; ++g) acc[mtl][g] = f32x4{0.f, 0.f, 0.f, 0.f};

      // ---- phase 1: h1(j-1) half (K 512..1023) -- only needs pB >= 32j ----
      block_wait(pB, 32u * (unsigned)j, pB, 0u);

      const unsigned short* src1 = h1x + ((j + 3) & 3) * 131072 + bt * 32768; // h1(j-1)
      #pragma unroll 4
      for (int ks = 16; ks < 32; ++ks) {
        int koff = (ks & 15) * 32;
        bf16x8 af[2];
        #pragma unroll
        for (int mtl = 0; mtl < 2; ++mtl)
          af[mtl] = ld_coh16(src1 + arowOff[mtl] + koff + l4 * 8);
        bf16x8 b0 = *(const bf16x8*)(wlds + (hh * 16 + l15) * B0STRIDE + ks * 32 + l4 * 8);
        #pragma unroll
        for (int mtl = 0; mtl < 2; ++mtl)
          acc[mtl][0] = __builtin_amdgcn_mfma_f32_16x16x32_bf16(af[mtl], b0, acc[mtl][0], 0, 0, 0);
        if (hh == 1) {
          bf16x8 b1 = *(const bf16x8*)(wlds + R2BASE + l15 * BSTRIDE + (ks - 16) * 32 + l4 * 8);
          #pragma unroll
          for (int mtl = 0; mtl < 2; ++mtl)
            acc[mtl][1] = __builtin_amdgcn_mfma_f32_16x16x32_bf16(af[mtl], b1, acc[mtl][1], 0, 0, 0);
        }
      }

      // ---- phase 2: h0(j) half (K 0..511) -- needs pA >= 16(j+1) ----
      block_wait(pA, 16u * (unsigned)(j + 1), pA, 0u);

      const unsigned short* src0 = h0x + (j & 3) * 131072 + bt * 32768;       // h0(j)
      #pragma unroll 4
      for (int ks = 0; ks < 16; ++ks) {
        bf16x8 af[2];
        #pragma unroll
        for (int mtl = 0; mtl < 2; ++mtl)
          af[mtl] = ld_coh16(src0 + arowOff[mtl] + ks * 32 + l4 * 8);
        bf16x8 b0 = *(const bf16x8*)(wlds + (hh * 16 + l15) * B0STRIDE + ks * 32 + l4 * 8);
        #pragma unroll
        for (int mtl = 0; mtl < 2; ++mtl)
          acc[mtl][0] = __builtin_amdgcn_mfma_f32_16x16x32_bf16(af[mtl], b0, acc[mtl][0], 0, 0, 0);
        if (hh == 0) {
          bf16x8 b1 = *(const bf16x8*)(wlds + R1BASE + l15 * BSTRIDE + ks * 32 + l4 * 8);
          #pragma unroll
          for (int mtl = 0; mtl < 2; ++mtl)
            acc[mtl][1] = __builtin_amdgcn_mfma_f32_16x16x32_bf16(af[mtl], b1, acc[mtl][1], 0, 0, 0);
        }
      }

      // exchange r/in_ (hh0) -> hh1 waves
      if (hh == 0) {
        #pragma unroll
        for (int mtl = 0; mtl < 2; ++mtl)
          #pragma unroll
          for (int qn = 0; qn < 2; ++qn)
            #pragma unroll
            for (int q = 0; q < 4; ++q)
              exch[((p_ * 2 + qn) * 32 + mtl * 16 + l4 * 4 + q) * 17 + l15] = acc[mtl][qn][q];
      }
      __syncthreads();
      if (hh == 1) {
        float bir = fmisc[l15],      biz = fmisc[16 + l15], bin = fmisc[32 + l15];
        float bhr = fmisc[48 + l15], bhz = fmisc[64 + l15], bhn = fmisc[80 + l15];
        #pragma unroll
        for (int mtl = 0; mtl < 2; ++mtl)
          #pragma unroll
          for (int q = 0; q < 4; ++q) {
            float rv = exch[((p_ * 2 + 0) * 32 + mtl * 16 + l4 * 4 + q) * 17 + l15];
            float iv = exch[((p_ * 2 + 1) * 32 + mtl * 16 + l4 * 4 + q) * 17 + l15];
            float rg = sigf(rv + bir + bhr);
            float zg = sigf(acc[mtl][0][q] + biz + bhz);
            float ng = tanhf_(iv + bin + rg * (acc[mtl][1][q] + bhn));
            float hv = (1.0f - zg) * ng + zg * carry[mtl][q];
            carry[mtl][q] = hv;
            sxu[((p_ * 2 + mtl) * 16 + l4 * 4 + q) * 16 + l15] = f2bf(hv);  // repack
            if (j == TN - 1) atomicAdd(&out[rowb[mtl][q]], hv * wout);      // projection
          }
      }
      __syncthreads();
      {
        const unsigned long long* sxq = (const unsigned long long*)sxu;
        unsigned long long v = sxq[tid];
        unsigned short* dsth = h1x + (j & 3) * 131072
                             + (bt * 64 + (tid >> 2)) * 512 + S + (tid & 3) * 4;
        st_coh(dsth, v);
      }
      block_publish(pB);
    }
  }
}

extern "C" void kernel_launch(void* const* d_in, const int* in_sizes, int n_in,
                              void* d_out, int out_size, void* d_ws, size_t ws_size,
                              hipStream_t stream) {
  const float* x     = (const float*)d_in[0];
  const float* h0in  = (const float*)d_in[1];
  const float* h1in  = (const float*)d_in[2];
  const float* W_ih1 = (const float*)d_in[3];
  const float* W_hh1 = (const float*)d_in[4];
  const float* b_ih1 = (const float*)d_in[5];
  const float* b_hh1 = (const float*)d_in[6];
  const float* W_ih2 = (const float*)d_in[7];
  const float* W_hh2 = (const float*)d_in[8];
  const float* b_ih2 = (const float*)d_in[9];
  const float* b_hh2 = (const float*)d_in[10];
  const float* W_out = (const float*)d_in[11];
  const float* b_out = (const float*)d_in[12];
  float* out = (float*)d_out;
  char* ws = (char*)d_ws;

  (void)in_sizes; (void)n_in; (void)out_size; (void)ws_size;

  hipFuncSetAttribute((const void*)gru_main,
                      hipFuncAttributeMaxDynamicSharedMemorySize, SMEM_BYTES);

  hipLaunchKernelGGL(gru_init, dim3(512), dim3(256), 0, stream,
                     h0in, h1in, b_out, out, ws);

  void* args[] = { (void*)&x,
                   (void*)&W_ih1, (void*)&W_hh1, (void*)&b_ih1, (void*)&b_hh1,
                   (void*)&W_ih2, (void*)&W_hh2, (void*)&b_ih2, (void*)&b_hh2,
                   (void*)&W_out, (void*)&b_out,
                   (void*)&h0in, (void*)&h1in,
                   (void*)&out, (void*)&ws };
  hipLaunchCooperativeKernel((const void*)gru_main, dim3(NBLK), dim3(256),
                             args, SMEM_BYTES, stream);
}

// Round 16
// 36859.659 us; speedup vs baseline: 1.3578x; 1.0025x over previous
//
#include <hip/hip_runtime.h>
#include <stdint.h>

// ---------------- problem constants ----------------
#define TN     2048     // time steps
#define NBLK   192      // 4 groups x (16 A-blocks + 32 B-blocks)

// LDS layout (pad strides == 6 mod 32 words -> ~2-way bank aliasing, free):
#define ASTRIDE  524
#define B0STRIDE 1036
#define BSTRIDE  524
#define R1BASE   33152          // 32*1036
#define R2BASE   41536          // R1BASE + 16*524
#define EXCH_OFF  100608
#define SX_OFF    109312
#define FMISC_OFF 113408
#define SMEM_BYTES 114688

// ws layout:
//   0       : h0x bf16 [4 slots][256][512]   (1 MiB)   slot(t)=t&3; t=-1 -> slot 3
//   1048576 : h1x bf16 [4 slots][256][512]   (1 MiB)
//   2097152 : counters u32[256]; group g: prodA at g*64, prodB at g*64+32
#define H0_OFF  0
#define H1_OFF  1048576
#define CNT_OFF 2097152

typedef __attribute__((ext_vector_type(8))) short bf16x8;
typedef __attribute__((ext_vector_type(4))) float f32x4;

__device__ __forceinline__ float sigf(float v)   { return 1.0f / (1.0f + __expf(-v)); }
__device__ __forceinline__ float tanhf_(float v) { return 2.0f / (1.0f + __expf(-2.0f * v)) - 1.0f; }
__device__ __forceinline__ unsigned short f2bf(float f) {
  unsigned u = __float_as_uint(f);
  u += 0x7fffu + ((u >> 16) & 1u);   // RNE
  return (unsigned short)(u >> 16);
}

// L2-bypassing (agent-scope, sc1) 16B fragment load from the IF coherence
// point -- no cache-maintenance op needed to observe remote writes.
__device__ __forceinline__ bf16x8 ld_coh16(const unsigned short* p) {
  union { unsigned long long q[2]; bf16x8 v; } u;
  u.q[0] = __hip_atomic_load((const unsigned long long*)p,
                             __ATOMIC_RELAXED, __HIP_MEMORY_SCOPE_AGENT);
  u.q[1] = __hip_atomic_load((const unsigned long long*)p + 1,
                             __ATOMIC_RELAXED, __HIP_MEMORY_SCOPE_AGENT);
  return u.v;
}

// Re-run safe init: state mirrors (slot 3), out = b_out, counters = 0.
extern "C" __global__ void gru_init(const float* __restrict__ h0,
                                    const float* __restrict__ h1,
                                    const float* __restrict__ b_out,
                                    float* __restrict__ out,
                                    char* __restrict__ ws) {
  int i = blockIdx.x * 256 + threadIdx.x;     // 512 blocks
  unsigned short* h0x = (unsigned short*)(ws + H0_OFF);
  unsigned short* h1x = (unsigned short*)(ws + H1_OFF);
  h0x[3 * 131072 + i] = f2bf(h0[i]);
  h1x[3 * 131072 + i] = f2bf(h1[i]);
  if (blockIdx.x == 0) out[threadIdx.x] = b_out[0];
  if (blockIdx.x == 1) ((unsigned*)(ws + CNT_OFF))[threadIdx.x] = 0u;
}

extern "C" __global__ void __launch_bounds__(256, 1)
gru_main(const float* __restrict__ x,
         const float* __restrict__ W_ih1, const float* __restrict__ W_hh1,
         const float* __restrict__ b_ih1, const float* __restrict__ b_hh1,
         const float* __restrict__ W_ih2, const float* __restrict__ W_hh2,
         const float* __restrict__ b_ih2, const float* __restrict__ b_hh2,
         const float* __restrict__ W_out, const float* __restrict__ b_out,
         const float* __restrict__ h0in, const float* __restrict__ h1in,
         float* __restrict__ out, char* __restrict__ ws)
{
  extern __shared__ char smem[];
  unsigned short* wlds = (unsigned short*)smem;
  float* exch  = (float*)(smem + EXCH_OFF);
  unsigned short* sxu = (unsigned short*)(smem + SX_OFF);
  float* fmisc = (float*)(smem + FMISC_OFF);

  unsigned short* h0x = (unsigned short*)(ws + H0_OFF);
  unsigned short* h1x = (unsigned short*)(ws + H1_OFF);

  const int bid = blockIdx.x, tid = threadIdx.x;
  const int w = tid >> 6, l = tid & 63, l15 = l & 15, l4 = l >> 4;
  const int p_ = w >> 1;     // M half: rows 0-31 / 32-63 of the 64-row batch tile
  const int hh = w & 1;      // A: column half; B: gate role (r,in_ / z,hn)

  // group mapping, XCD-aware: blocks bid%8 in {2g,2g+1} form group g
  const int bt  = (bid & 7) >> 1;                 // group = batch tile
  const int sub = (bid >> 3) * 2 + (bid & 1);     // 0..47 within group
  const bool isA = (sub < 16);
  const int S = isA ? sub * 32 : (sub - 16) * 16;

  unsigned* pA = (unsigned*)(ws + CNT_OFF) + bt * 64;
  unsigned* pB = pA + 32;

  // ---------------- weight preload into LDS (bf16) ----------------
  if (isA) {
    for (int idx = tid; idx < 96 * 512; idx += 256) {
      int j = idx >> 9, kk = idx & 511;
      int h = j / 48, rr = j % 48, g = rr >> 4, c2 = rr & 15;
      int grow = g * 512 + S + h * 16 + c2;
      wlds[j * ASTRIDE + kk] = f2bf(W_hh1[grow * 512 + kk]);
    }
    if (tid < 96) {
      int j = tid, h = j / 48, rr = j % 48, g = rr >> 4, c2 = rr & 15;
      int grow = g * 512 + S + h * 16 + c2;
      fmisc[j]       = W_ih1[grow];
      fmisc[96 + j]  = b_ih1[grow];
      fmisc[192 + j] = b_hh1[grow];
    }
  } else {
    // region0: rows 0..15 = r-gate, 16..31 = z-gate; K=1024 = [W_ih2 | W_hh2]
    for (int idx = tid; idx < 32 * 1024; idx += 256) {
      int j = idx >> 10, kk = idx & 1023;
      int g = j >> 4, c2 = S + (j & 15);
      float v = (kk < 512) ? W_ih2[(g * 512 + c2) * 512 + kk]
                           : W_hh2[(g * 512 + c2) * 512 + kk - 512];
      wlds[j * B0STRIDE + kk] = f2bf(v);
    }
    // region1: in_ rows (W_ih2 n-gate); region2: hn rows (W_hh2 n-gate); K=512
    for (int idx = tid; idx < 16 * 512; idx += 256) {
      int j2 = idx >> 9, kk = idx & 511;
      wlds[R1BASE + j2 * BSTRIDE + kk] = f2bf(W_ih2[(1024 + S + j2) * 512 + kk]);
      wlds[R2BASE + j2 * BSTRIDE + kk] = f2bf(W_hh2[(1024 + S + j2) * 512 + kk]);
    }
    if (tid < 48) {
      int g = tid >> 4, c2 = S + (tid & 15);
      fmisc[tid]      = b_ih2[g * 512 + c2];
      fmisc[48 + tid] = b_hh2[g * 512 + c2];
    }
  }
  __syncthreads();

  // ---------------- per-thread constants / carries ----------------
  int rowb[2][4];
  int arowOff[2];
  #pragma unroll
  for (int mtl = 0; mtl < 2; ++mtl) {
    arowOff[mtl] = ((p_ * 2 + mtl) * 16 + l15) * 512;     // A-fragment row (lane&15-based)
    #pragma unroll
    for (int q = 0; q < 4; ++q)
      rowb[mtl][q] = bt * 64 + (p_ * 2 + mtl) * 16 + l4 * 4 + q;  // D row (reg-based)
  }

  float carry[2][4];
  #pragma unroll
  for (int mtl = 0; mtl < 2; ++mtl)
    #pragma unroll
    for (int q = 0; q < 4; ++q) carry[mtl][q] = 0.0f;
  if (isA) {
    int c = S + hh * 16 + l15;
    #pragma unroll
    for (int mtl = 0; mtl < 2; ++mtl)
      #pragma unroll
      for (int q = 0; q < 4; ++q) carry[mtl][q] = h0in[rowb[mtl][q] * 512 + c];
  } else if (hh == 1) {
    int c = S + l15;
    #pragma unroll
    for (int mtl = 0; mtl < 2; ++mtl)
      #pragma unroll
      for (int q = 0; q < 4; ++q) carry[mtl][q] = h1in[rowb[mtl][q] * 512 + c];
  }
  const float wout = (!isA && hh == 1) ? W_out[S + l15] : 0.0f;

  int dead = 0;   // only tid0's copy matters

  // wait until *c0 >= t0 && *c1 >= t1 (tid0 polls relaxed/sc1).
  // BACKOFF polling: one immediate fast-path check, then ~1.5K-cycle sleeps.
  auto block_wait = [&](unsigned* c0, unsigned t0, unsigned* c1, unsigned t1) {
    if (tid == 0 && !dead) {
      if (__hip_atomic_load(c0, __ATOMIC_RELAXED, __HIP_MEMORY_SCOPE_AGENT) < t0 ||
          __hip_atomic_load(c1, __ATOMIC_RELAXED, __HIP_MEMORY_SCOPE_AGENT) < t1) {
        int spins = 0;
        for (;;) {
          __builtin_amdgcn_s_sleep(24);   // backoff FIRST, then re-check
          if (__hip_atomic_load(c0, __ATOMIC_RELAXED, __HIP_MEMORY_SCOPE_AGENT) >= t0 &&
              __hip_atomic_load(c1, __ATOMIC_RELAXED, __HIP_MEMORY_SCOPE_AGENT) >= t1) break;
          if (++spins > 30000) { dead = 1; break; }   // bounded failure, no hang
        }
      }
    }
    __syncthreads();
  };
  // publisher: all state stores are sc1 write-through; drain them, then relaxed add
  auto block_publish = [&](unsigned* c) {
    asm volatile("s_waitcnt vmcnt(0)" ::: "memory");
    __syncthreads();
    if (tid == 0) __hip_atomic_fetch_add(c, 1u, __ATOMIC_RELAXED, __HIP_MEMORY_SCOPE_AGENT);
  };
  // coherent (IF-level, sc1) u64 store of repacked state
  auto st_coh = [&](unsigned short* p, unsigned long long v) {
    __hip_atomic_store((unsigned long long*)p, v, __ATOMIC_RELAXED, __HIP_MEMORY_SCOPE_AGENT);
  };

  if (isA) {
    // ============ cell-1 blocks: compute h0(k), k = 0..TN-1 ============
    for (int k = 0; k < TN; ++k) {
      // x column loads are flag-independent: issue before the wait
      float xv[2][4];
      #pragma unroll
      for (int mtl = 0; mtl < 2; ++mtl)
        #pragma unroll
        for (int q = 0; q < 4; ++q) xv[mtl][q] = x[rowb[mtl][q] * 2048 + k];

      block_wait(pA, 16u * (unsigned)k,
                 pB, (k >= 3) ? 32u * (unsigned)(k - 3) : 0u);

      f32x4 acc[2][3];
      #pragma unroll
      for (int mtl = 0; mtl < 2; ++mtl)
        #pragma unroll
        for (int g = 0; g < 3; ++g) acc[mtl][g] = f32x4{0.f, 0.f, 0.f, 0.f};

      const unsigned short* srcA = h0x + ((k + 3) & 3) * 131072 + bt * 32768; // h0(k-1)
      #pragma unroll 4
      for (int ks = 0; ks < 16; ++ks) {
        bf16x8 af[2];
        #pragma unroll
        for (int mtl = 0; mtl < 2; ++mtl)
          af[mtl] = ld_coh16(srcA + arowOff[mtl] + ks * 32 + l4 * 8);
        #pragma unroll
        for (int g = 0; g < 3; ++g) {
          bf16x8 bw = *(const bf16x8*)(wlds + (hh * 48 + g * 16 + l15) * ASTRIDE + ks * 32 + l4 * 8);
          #pragma unroll
          for (int mtl = 0; mtl < 2; ++mtl)
            acc[mtl][g] = __builtin_amdgcn_mfma_f32_16x16x32_bf16(af[mtl], bw, acc[mtl][g], 0, 0, 0);
        }
      }

      int cc = hh * 16 + l15;          // local column 0..31
      int jb = hh * 48 + l15;
      float wir = fmisc[jb],       wiz = fmisc[jb + 16],       win = fmisc[jb + 32];
      float bir = fmisc[96 + jb],  biz = fmisc[96 + jb + 16],  bin = fmisc[96 + jb + 32];
      float bhr = fmisc[192 + jb], bhz = fmisc[192 + jb + 16], bhn = fmisc[192 + jb + 32];
      #pragma unroll
      for (int mtl = 0; mtl < 2; ++mtl)
        #pragma unroll
        for (int q = 0; q < 4; ++q) {
          float rg = sigf(xv[mtl][q] * wir + bir + acc[mtl][0][q] + bhr);
          float zg = sigf(xv[mtl][q] * wiz + biz + acc[mtl][1][q] + bhz);
          float ng = tanhf_(xv[mtl][q] * win + bin + rg * (acc[mtl][2][q] + bhn));
          float hv = (1.0f - zg) * ng + zg * carry[mtl][q];
          carry[mtl][q] = hv;
          sxu[((p_ * 2 + mtl) * 16 + l4 * 4 + q) * 32 + cc] = f2bf(hv);  // repack
        }
      __syncthreads();
      {
        const unsigned long long* sxq = (const unsigned long long*)sxu;
        unsigned long long v0 = sxq[tid * 2], v1 = sxq[tid * 2 + 1];
        unsigned short* dsth = h0x + (k & 3) * 131072
                             + (bt * 64 + (tid >> 2)) * 512 + S + (tid & 3) * 8;
        st_coh(dsth, v0);
        st_coh(dsth + 4, v1);
      }
      block_publish(pA);
    }
  } else {
    // ============ cell-2 blocks: compute h1(j), j = 0..TN-1 ============
    for (int j = 0; j < TN; ++j) {
      f32x4 acc[2][2];
      #pragma unroll
      for (int mtl = 0; mtl < 2; ++mtl)
        #pragma unroll
        for (int g = 0; g < 2; ++g) acc[mtl][g] = f32x4{0.f, 0.f, 0.f, 0.f};

      // ---- phase 1: h1(j-1) half (K 512..1023) -- only needs pB >= 32j ----
      block_wait(pB, 32u * (unsigned)j, pB, 0u);

      const unsigned short* src1 = h1x + ((j + 3) & 3) * 131072 + bt * 32768; // h1(j-1)
      #pragma unroll 4
      for (int ks = 16; ks < 32; ++ks) {
        int koff = (ks & 15) * 32;
        bf16x8 af[2];
        #pragma unroll
        for (int mtl = 0; mtl < 2; ++mtl)
          af[mtl] = ld_coh16(src1 + arowOff[mtl] + koff + l4 * 8);
        bf16x8 b0 = *(const bf16x8*)(wlds + (hh * 16 + l15) * B0STRIDE + ks * 32 + l4 * 8);
        #pragma unroll
        for (int mtl = 0; mtl < 2; ++mtl)
          acc[mtl][0] = __builtin_amdgcn_mfma_f32_16x16x32_bf16(af[mtl], b0, acc[mtl][0], 0, 0, 0);
        if (hh == 1) {
          bf16x8 b1 = *(const bf16x8*)(wlds + R2BASE + l15 * BSTRIDE + (ks - 16) * 32 + l4 * 8);
          #pragma unroll
          for (int mtl = 0; mtl < 2; ++mtl)
            acc[mtl][1] = __builtin_amdgcn_mfma_f32_16x16x32_bf16(af[mtl], b1, acc[mtl][1], 0, 0, 0);
        }
      }

      // ---- phase 2: h0(j) half (K 0..511) -- needs pA >= 16(j+1) ----
      block_wait(pA, 16u * (unsigned)(j + 1), pA, 0u);

      const unsigned short* src0 = h0x + (j & 3) * 131072 + bt * 32768;       // h0(j)
      #pragma unroll 4
      for (int ks = 0; ks < 16; ++ks) {
        bf16x8 af[2];
        #pragma unroll
        for (int mtl = 0; mtl < 2; ++mtl)
          af[mtl] = ld_coh16(src0 + arowOff[mtl] + ks * 32 + l4 * 8);
        bf16x8 b0 = *(const bf16x8*)(wlds + (hh * 16 + l15) * B0STRIDE + ks * 32 + l4 * 8);
        #pragma unroll
        for (int mtl = 0; mtl < 2; ++mtl)
          acc[mtl][0] = __builtin_amdgcn_mfma_f32_16x16x32_bf16(af[mtl], b0, acc[mtl][0], 0, 0, 0);
        if (hh == 0) {
          bf16x8 b1 = *(const bf16x8*)(wlds + R1BASE + l15 * BSTRIDE + ks * 32 + l4 * 8);
          #pragma unroll
          for (int mtl = 0; mtl < 2; ++mtl)
            acc[mtl][1] = __builtin_amdgcn_mfma_f32_16x16x32_bf16(af[mtl], b1, acc[mtl][1], 0, 0, 0);
        }
      }

      // exchange r/in_ (hh0) -> hh1 waves
      if (hh == 0) {
        #pragma unroll
        for (int mtl = 0; mtl < 2; ++mtl)
          #pragma unroll
          for (int qn = 0; qn < 2; ++qn)
            #pragma unroll
            for (int q = 0; q < 4; ++q)
              exch[((p_ * 2 + qn) * 32 + mtl * 16 + l4 * 4 + q) * 17 + l15] = acc[mtl][qn][q];
      }
      __syncthreads();
      if (hh == 1) {
        float bir = fmisc[l15],      biz = fmisc[16 + l15], bin = fmisc[32 + l15];
        float bhr = fmisc[48 + l15], bhz = fmisc[64 + l15], bhn = fmisc[80 + l15];
        #pragma unroll
        for (int mtl = 0; mtl < 2; ++mtl)
          #pragma unroll
          for (int q = 0; q < 4; ++q) {
            float rv = exch[((p_ * 2 + 0) * 32 + mtl * 16 + l4 * 4 + q) * 17 + l15];
            float iv = exch[((p_ * 2 + 1) * 32 + mtl * 16 + l4 * 4 + q) * 17 + l15];
            float rg = sigf(rv + bir + bhr);
            float zg = sigf(acc[mtl][0][q] + biz + bhz);
            float ng = tanhf_(iv + bin + rg * (acc[mtl][1][q] + bhn));
            float hv = (1.0f - zg) * ng + zg * carry[mtl][q];
            carry[mtl][q] = hv;
            sxu[((p_ * 2 + mtl) * 16 + l4 * 4 + q) * 16 + l15] = f2bf(hv);  // repack
            if (j == TN - 1) atomicAdd(&out[rowb[mtl][q]], hv * wout);      // projection
          }
      }
      __syncthreads();
      {
        const unsigned long long* sxq = (const unsigned long long*)sxu;
        unsigned long long v = sxq[tid];
        unsigned short* dsth = h1x + (j & 3) * 131072
                             + (bt * 64 + (tid >> 2)) * 512 + S + (tid & 3) * 4;
        st_coh(dsth, v);
      }
      block_publish(pB);
    }
  }
}

extern "C" void kernel_launch(void* const* d_in, const int* in_sizes, int n_in,
                              void* d_out, int out_size, void* d_ws, size_t ws_size,
                              hipStream_t stream) {
  const float* x     = (const float*)d_in[0];
  const float* h0in  = (const float*)d_in[1];
  const float* h1in  = (const float*)d_in[2];
  const float* W_ih1 = (const float*)d_in[3];
  const float* W_hh1 = (const float*)d_in[4];
  const float* b_ih1 = (const float*)d_in[5];
  const float* b_hh1 = (const float*)d_in[6];
  const float* W_ih2 = (const float*)d_in[7];
  const float* W_hh2 = (const float*)d_in[8];
  const float* b_ih2 = (const float*)d_in[9];
  const float* b_hh2 = (const float*)d_in[10];
  const float* W_out = (const float*)d_in[11];
  const float* b_out = (const float*)d_in[12];
  float* out = (float*)d_out;
  char* ws = (char*)d_ws;

  (void)in_sizes; (void)n_in; (void)out_size; (void)ws_size;

  hipFuncSetAttribute((const void*)gru_main,
                      hipFuncAttributeMaxDynamicSharedMemorySize, SMEM_BYTES);

  hipLaunchKernelGGL(gru_init, dim3(512), dim3(256), 0, stream,
                     h0in, h1in, b_out, out, ws);

  void* args[] = { (void*)&x,
                   (void*)&W_ih1, (void*)&W_hh1, (void*)&b_ih1, (void*)&b_hh1,
                   (void*)&W_ih2, (void*)&W_hh2, (void*)&b_ih2, (void*)&b_hh2,
                   (void*)&W_out, (void*)&b_out,
                   (void*)&h0in, (void*)&h1in,
                   (void*)&out, (void*)&ws };
  hipLaunchCooperativeKernel((const void*)gru_main, dim3(NBLK), dim3(256),
                             args, SMEM_BYTES, stream);
}

// Round 17
// 34670.013 us; speedup vs baseline: 1.4436x; 1.0632x over previous
//
#include <hip/hip_runtime.h>
#include <stdint.h>

// ---------------- problem constants ----------------
#define TN     2048     // time steps
#define NBLK   192      // 4 groups x (16 A-blocks + 32 B-blocks)

// LDS layout (pad strides == 6 mod 32 words -> ~2-way bank aliasing, free):
#define ASTRIDE  524
#define B0STRIDE 1036
#define BSTRIDE  524
#define R1BASE   33152          // 32*1036
#define R2BASE   41536          // R1BASE + 16*524
#define EXCH_OFF  100608
#define SX_OFF    109312
#define FMISC_OFF 113408
#define SMEM_BYTES 114688

// ws layout:
//   0       : h0x bf16 [4 slots][256][512]   (1 MiB)   slot(t)=t&3; t=-1 -> slot 3
//   1048576 : h1x bf16 [4 slots][256][512]   (1 MiB)
//   2097152 : counters u32[256]; group g: prodA at g*64, prodB at g*64+32
#define H0_OFF  0
#define H1_OFF  1048576
#define CNT_OFF 2097152

typedef __attribute__((ext_vector_type(8))) short bf16x8;
typedef __attribute__((ext_vector_type(4))) float f32x4;

__device__ __forceinline__ float sigf(float v)   { return 1.0f / (1.0f + __expf(-v)); }
__device__ __forceinline__ float tanhf_(float v) { return 2.0f / (1.0f + __expf(-2.0f * v)) - 1.0f; }
__device__ __forceinline__ unsigned short f2bf(float f) {
  unsigned u = __float_as_uint(f);
  u += 0x7fffu + ((u >> 16) & 1u);   // RNE
  return (unsigned short)(u >> 16);
}

// Agent-scope (IF coherence point) 16B fragment load -- proven R6-R16.
__device__ __forceinline__ bf16x8 ld_coh16(const unsigned short* p) {
  union { unsigned long long q[2]; bf16x8 v; } u;
  u.q[0] = __hip_atomic_load((const unsigned long long*)p,
                             __ATOMIC_RELAXED, __HIP_MEMORY_SCOPE_AGENT);
  u.q[1] = __hip_atomic_load((const unsigned long long*)p + 1,
                             __ATOMIC_RELAXED, __HIP_MEMORY_SCOPE_AGENT);
  return u.v;
}

// Re-run safe init: state mirrors (slot 3), out = b_out, counters = 0.
extern "C" __global__ void gru_init(const float* __restrict__ h0,
                                    const float* __restrict__ h1,
                                    const float* __restrict__ b_out,
                                    float* __restrict__ out,
                                    char* __restrict__ ws) {
  int i = blockIdx.x * 256 + threadIdx.x;     // 512 blocks
  unsigned short* h0x = (unsigned short*)(ws + H0_OFF);
  unsigned short* h1x = (unsigned short*)(ws + H1_OFF);
  h0x[3 * 131072 + i] = f2bf(h0[i]);
  h1x[3 * 131072 + i] = f2bf(h1[i]);
  if (blockIdx.x == 0) out[threadIdx.x] = b_out[0];
  if (blockIdx.x == 1) ((unsigned*)(ws + CNT_OFF))[threadIdx.x] = 0u;
}

extern "C" __global__ void __launch_bounds__(256, 1)
gru_main(const float* __restrict__ x,
         const float* __restrict__ W_ih1, const float* __restrict__ W_hh1,
         const float* __restrict__ b_ih1, const float* __restrict__ b_hh1,
         const float* __restrict__ W_ih2, const float* __restrict__ W_hh2,
         const float* __restrict__ b_ih2, const float* __restrict__ b_hh2,
         const float* __restrict__ W_out, const float* __restrict__ b_out,
         const float* __restrict__ h0in, const float* __restrict__ h1in,
         float* __restrict__ out, char* __restrict__ ws)
{
  extern __shared__ char smem[];
  unsigned short* wlds = (unsigned short*)smem;
  float* exch  = (float*)(smem + EXCH_OFF);
  unsigned short* sxu = (unsigned short*)(smem + SX_OFF);
  float* fmisc = (float*)(smem + FMISC_OFF);

  unsigned short* h0x = (unsigned short*)(ws + H0_OFF);
  unsigned short* h1x = (unsigned short*)(ws + H1_OFF);

  const int bid = blockIdx.x, tid = threadIdx.x;
  const int w = tid >> 6, l = tid & 63, l15 = l & 15, l4 = l >> 4;
  const int p_ = w >> 1;     // M half: rows 0-31 / 32-63 of the 64-row batch tile
  const int hh = w & 1;      // A: column half; B: gate role (r,in_ / z,hn)

  // group mapping, XCD-aware: blocks bid%8 in {2g,2g+1} form group g
  const int bt  = (bid & 7) >> 1;                 // group = batch tile
  const int sub = (bid >> 3) * 2 + (bid & 1);     // 0..47 within group
  const bool isA = (sub < 16);
  const int S = isA ? sub * 32 : (sub - 16) * 16;

  unsigned* pA = (unsigned*)(ws + CNT_OFF) + bt * 64;
  unsigned* pB = pA + 32;

  // ---------------- weight preload into LDS (bf16) ----------------
  if (isA) {
    for (int idx = tid; idx < 96 * 512; idx += 256) {
      int j = idx >> 9, kk = idx & 511;
      int h = j / 48, rr = j % 48, g = rr >> 4, c2 = rr & 15;
      int grow = g * 512 + S + h * 16 + c2;
      wlds[j * ASTRIDE + kk] = f2bf(W_hh1[grow * 512 + kk]);
    }
    if (tid < 96) {
      int j = tid, h = j / 48, rr = j % 48, g = rr >> 4, c2 = rr & 15;
      int grow = g * 512 + S + h * 16 + c2;
      fmisc[j]       = W_ih1[grow];
      fmisc[96 + j]  = b_ih1[grow];
      fmisc[192 + j] = b_hh1[grow];
    }
  } else {
    // region0: rows 0..15 = r-gate, 16..31 = z-gate; K=1024 = [W_ih2 | W_hh2]
    for (int idx = tid; idx < 32 * 1024; idx += 256) {
      int j = idx >> 10, kk = idx & 1023;
      int g = j >> 4, c2 = S + (j & 15);
      float v = (kk < 512) ? W_ih2[(g * 512 + c2) * 512 + kk]
                           : W_hh2[(g * 512 + c2) * 512 + kk - 512];
      wlds[j * B0STRIDE + kk] = f2bf(v);
    }
    // region1: in_ rows (W_ih2 n-gate); region2: hn rows (W_hh2 n-gate); K=512
    for (int idx = tid; idx < 16 * 512; idx += 256) {
      int j2 = idx >> 9, kk = idx & 511;
      wlds[R1BASE + j2 * BSTRIDE + kk] = f2bf(W_ih2[(1024 + S + j2) * 512 + kk]);
      wlds[R2BASE + j2 * BSTRIDE + kk] = f2bf(W_hh2[(1024 + S + j2) * 512 + kk]);
    }
    if (tid < 48) {
      int g = tid >> 4, c2 = S + (tid & 15);
      fmisc[tid]      = b_ih2[g * 512 + c2];
      fmisc[48 + tid] = b_hh2[g * 512 + c2];
    }
  }
  __syncthreads();

  // ---------------- per-thread constants / carries ----------------
  int rowb[2][4];
  int arowOff[2];
  #pragma unroll
  for (int mtl = 0; mtl < 2; ++mtl) {
    arowOff[mtl] = ((p_ * 2 + mtl) * 16 + l15) * 512;     // A-fragment row (lane&15-based)
    #pragma unroll
    for (int q = 0; q < 4; ++q)
      rowb[mtl][q] = bt * 64 + (p_ * 2 + mtl) * 16 + l4 * 4 + q;  // D row (reg-based)
  }

  float carry[2][4];
  #pragma unroll
  for (int mtl = 0; mtl < 2; ++mtl)
    #pragma unroll
    for (int q = 0; q < 4; ++q) carry[mtl][q] = 0.0f;
  if (isA) {
    int c = S + hh * 16 + l15;
    #pragma unroll
    for (int mtl = 0; mtl < 2; ++mtl)
      #pragma unroll
      for (int q = 0; q < 4; ++q) carry[mtl][q] = h0in[rowb[mtl][q] * 512 + c];
  } else if (hh == 1) {
    int c = S + l15;
    #pragma unroll
    for (int mtl = 0; mtl < 2; ++mtl)
      #pragma unroll
      for (int q = 0; q < 4; ++q) carry[mtl][q] = h1in[rowb[mtl][q] * 512 + c];
  }
  const float wout = (!isA && hh == 1) ? W_out[S + l15] : 0.0f;

  int dead = 0;   // only tid0's copy matters

  // wait until *c0 >= t0 && *c1 >= t1 (tid0 polls relaxed/sc1).
  // BACKOFF polling: one immediate fast-path check, then ~1.5K-cycle sleeps.
  auto block_wait = [&](unsigned* c0, unsigned t0, unsigned* c1, unsigned t1) {
    if (tid == 0 && !dead) {
      if (__hip_atomic_load(c0, __ATOMIC_RELAXED, __HIP_MEMORY_SCOPE_AGENT) < t0 ||
          __hip_atomic_load(c1, __ATOMIC_RELAXED, __HIP_MEMORY_SCOPE_AGENT) < t1) {
        int spins = 0;
        for (;;) {
          __builtin_amdgcn_s_sleep(24);   // backoff FIRST, then re-check
          if (__hip_atomic_load(c0, __ATOMIC_RELAXED, __HIP_MEMORY_SCOPE_AGENT) >= t0 &&
              __hip_atomic_load(c1, __ATOMIC_RELAXED, __HIP_MEMORY_SCOPE_AGENT) >= t1) break;
          if (++spins > 30000) { dead = 1; break; }   // bounded failure, no hang
        }
      }
    }
    __syncthreads();
  };
  // publisher: all state stores are sc1 write-through; drain them, then relaxed add
  auto block_publish = [&](unsigned* c) {
    asm volatile("s_waitcnt vmcnt(0)" ::: "memory");
    __syncthreads();
    if (tid == 0) __hip_atomic_fetch_add(c, 1u, __ATOMIC_RELAXED, __HIP_MEMORY_SCOPE_AGENT);
  };
  // coherent (IF-level, sc1) u64 store of repacked state
  auto st_coh = [&](unsigned short* p, unsigned long long v) {
    __hip_atomic_store((unsigned long long*)p, v, __ATOMIC_RELAXED, __HIP_MEMORY_SCOPE_AGENT);
  };

  if (isA) {
    // ============ cell-1 blocks: compute h0(k), k = 0..TN-1 ============
    for (int k = 0; k < TN; ++k) {
      // x column loads are flag-independent: issue before the wait
      float xv[2][4];
      #pragma unroll
      for (int mtl = 0; mtl < 2; ++mtl)
        #pragma unroll
        for (int q = 0; q < 4; ++q) xv[mtl][q] = x[rowb[mtl][q] * 2048 + k];

      block_wait(pA, 16u * (unsigned)k,
                 pB, (k >= 3) ? 32u * (unsigned)(k - 3) : 0u);

      f32x4 acc[2][3];
      #pragma unroll
      for (int mtl = 0; mtl < 2; ++mtl)
        #pragma unroll
        for (int g = 0; g < 3; ++g) acc[mtl][g] = f32x4{0.f, 0.f, 0.f, 0.f};

      const unsigned short* srcA = h0x + ((k + 3) & 3) * 131072 + bt * 32768; // h0(k-1)
      #pragma unroll 4
      for (int ks = 0; ks < 16; ++ks) {
        bf16x8 af[2];
        #pragma unroll
        for (int mtl = 0; mtl < 2; ++mtl)
          af[mtl] = ld_coh16(srcA + arowOff[mtl] + ks * 32 + l4 * 8);
        #pragma unroll
        for (int g = 0; g < 3; ++g) {
          bf16x8 bw = *(const bf16x8*)(wlds + (hh * 48 + g * 16 + l15) * ASTRIDE + ks * 32 + l4 * 8);
          #pragma unroll
          for (int mtl = 0; mtl < 2; ++mtl)
            acc[mtl][g] = __builtin_amdgcn_mfma_f32_16x16x32_bf16(af[mtl], bw, acc[mtl][g], 0, 0, 0);
        }
      }

      int cc = hh * 16 + l15;          // local column 0..31
      int jb = hh * 48 + l15;
      float wir = fmisc[jb],       wiz = fmisc[jb + 16],       win = fmisc[jb + 32];
      float bir = fmisc[96 + jb],  biz = fmisc[96 + jb + 16],  bin = fmisc[96 + jb + 32];
      float bhr = fmisc[192 + jb], bhz = fmisc[192 + jb + 16], bhn = fmisc[192 + jb + 32];
      #pragma unroll
      for (int mtl = 0; mtl < 2; ++mtl)
        #pragma unroll
        for (int q = 0; q < 4; ++q) {
          float rg = sigf(xv[mtl][q] * wir + bir + acc[mtl][0][q] + bhr);
          float zg = sigf(xv[mtl][q] * wiz + biz + acc[mtl][1][q] + bhz);
          float ng = tanhf_(xv[mtl][q] * win + bin + rg * (acc[mtl][2][q] + bhn));
          float hv = (1.0f - zg) * ng + zg * carry[mtl][q];
          carry[mtl][q] = hv;
          sxu[((p_ * 2 + mtl) * 16 + l4 * 4 + q) * 32 + cc] = f2bf(hv);  // repack
        }
      __syncthreads();
      {
        const unsigned long long* sxq = (const unsigned long long*)sxu;
        unsigned long long v0 = sxq[tid * 2], v1 = sxq[tid * 2 + 1];
        unsigned short* dsth = h0x + (k & 3) * 131072
                             + (bt * 64 + (tid >> 2)) * 512 + S + (tid & 3) * 8;
        st_coh(dsth, v0);
        st_coh(dsth + 4, v1);
      }
      block_publish(pA);
    }
  } else {
    // ============ cell-2 blocks: compute h1(j), j = 0..TN-1 ============
    // PHASE ORDER SWAPPED vs R14: consume OLD data (h0(j), published a full
    // tick ago by the ahead-running A) first; the FRESH pB dependency's
    // store-drain + IF-visibility + straggler window hides under that work.
    for (int j = 0; j < TN; ++j) {
      f32x4 acc[2][2];
      #pragma unroll
      for (int mtl = 0; mtl < 2; ++mtl)
        #pragma unroll
        for (int g = 0; g < 2; ++g) acc[mtl][g] = f32x4{0.f, 0.f, 0.f, 0.f};

      // ---- phase 1: h0(j) half (K 0..511) -- needs pA >= 16(j+1) [usually instant] ----
      block_wait(pA, 16u * (unsigned)(j + 1), pA, 0u);

      const unsigned short* src0 = h0x + (j & 3) * 131072 + bt * 32768;       // h0(j)
      #pragma unroll 4
      for (int ks = 0; ks < 16; ++ks) {
        bf16x8 af[2];
        #pragma unroll
        for (int mtl = 0; mtl < 2; ++mtl)
          af[mtl] = ld_coh16(src0 + arowOff[mtl] + ks * 32 + l4 * 8);
        bf16x8 b0 = *(const bf16x8*)(wlds + (hh * 16 + l15) * B0STRIDE + ks * 32 + l4 * 8);
        #pragma unroll
        for (int mtl = 0; mtl < 2; ++mtl)
          acc[mtl][0] = __builtin_amdgcn_mfma_f32_16x16x32_bf16(af[mtl], b0, acc[mtl][0], 0, 0, 0);
        if (hh == 0) {
          bf16x8 b1 = *(const bf16x8*)(wlds + R1BASE + l15 * BSTRIDE + ks * 32 + l4 * 8);
          #pragma unroll
          for (int mtl = 0; mtl < 2; ++mtl)
            acc[mtl][1] = __builtin_amdgcn_mfma_f32_16x16x32_bf16(af[mtl], b1, acc[mtl][1], 0, 0, 0);
        }
      }

      // ---- phase 2: h1(j-1) half (K 512..1023) -- needs pB >= 32j (visibility hidden) ----
      block_wait(pB, 32u * (unsigned)j, pB, 0u);

      const unsigned short* src1 = h1x + ((j + 3) & 3) * 131072 + bt * 32768; // h1(j-1)
      #pragma unroll 4
      for (int ks = 16; ks < 32; ++ks) {
        int koff = (ks & 15) * 32;
        bf16x8 af[2];
        #pragma unroll
        for (int mtl = 0; mtl < 2; ++mtl)
          af[mtl] = ld_coh16(src1 + arowOff[mtl] + koff + l4 * 8);
        bf16x8 b0 = *(const bf16x8*)(wlds + (hh * 16 + l15) * B0STRIDE + ks * 32 + l4 * 8);
        #pragma unroll
        for (int mtl = 0; mtl < 2; ++mtl)
          acc[mtl][0] = __builtin_amdgcn_mfma_f32_16x16x32_bf16(af[mtl], b0, acc[mtl][0], 0, 0, 0);
        if (hh == 1) {
          bf16x8 b1 = *(const bf16x8*)(wlds + R2BASE + l15 * BSTRIDE + (ks - 16) * 32 + l4 * 8);
          #pragma unroll
          for (int mtl = 0; mtl < 2; ++mtl)
            acc[mtl][1] = __builtin_amdgcn_mfma_f32_16x16x32_bf16(af[mtl], b1, acc[mtl][1], 0, 0, 0);
        }
      }

      // exchange r/in_ (hh0) -> hh1 waves
      if (hh == 0) {
        #pragma unroll
        for (int mtl = 0; mtl < 2; ++mtl)
          #pragma unroll
          for (int qn = 0; qn < 2; ++qn)
            #pragma unroll
            for (int q = 0; q < 4; ++q)
              exch[((p_ * 2 + qn) * 32 + mtl * 16 + l4 * 4 + q) * 17 + l15] = acc[mtl][qn][q];
      }
      __syncthreads();
      if (hh == 1) {
        float bir = fmisc[l15],      biz = fmisc[16 + l15], bin = fmisc[32 + l15];
        float bhr = fmisc[48 + l15], bhz = fmisc[64 + l15], bhn = fmisc[80 + l15];
        #pragma unroll
        for (int mtl = 0; mtl < 2; ++mtl)
          #pragma unroll
          for (int q = 0; q < 4; ++q) {
            float rv = exch[((p_ * 2 + 0) * 32 + mtl * 16 + l4 * 4 + q) * 17 + l15];
            float iv = exch[((p_ * 2 + 1) * 32 + mtl * 16 + l4 * 4 + q) * 17 + l15];
            float rg = sigf(rv + bir + bhr);
            float zg = sigf(acc[mtl][0][q] + biz + bhz);
            float ng = tanhf_(iv + bin + rg * (acc[mtl][1][q] + bhn));
            float hv = (1.0f - zg) * ng + zg * carry[mtl][q];
            carry[mtl][q] = hv;
            sxu[((p_ * 2 + mtl) * 16 + l4 * 4 + q) * 16 + l15] = f2bf(hv);  // repack
            if (j == TN - 1) atomicAdd(&out[rowb[mtl][q]], hv * wout);      // projection
          }
      }
      __syncthreads();
      {
        const unsigned long long* sxq = (const unsigned long long*)sxu;
        unsigned long long v = sxq[tid];
        unsigned short* dsth = h1x + (j & 3) * 131072
                             + (bt * 64 + (tid >> 2)) * 512 + S + (tid & 3) * 4;
        st_coh(dsth, v);
      }
      block_publish(pB);
    }
  }
}

extern "C" void kernel_launch(void* const* d_in, const int* in_sizes, int n_in,
                              void* d_out, int out_size, void* d_ws, size_t ws_size,
                              hipStream_t stream) {
  const float* x     = (const float*)d_in[0];
  const float* h0in  = (const float*)d_in[1];
  const float* h1in  = (const float*)d_in[2];
  const float* W_ih1 = (const float*)d_in[3];
  const float* W_hh1 = (const float*)d_in[4];
  const float* b_ih1 = (const float*)d_in[5];
  const float* b_hh1 = (const float*)d_in[6];
  const float* W_ih2 = (const float*)d_in[7];
  const float* W_hh2 = (const float*)d_in[8];
  const float* b_ih2 = (const float*)d_in[9];
  const float* b_hh2 = (const float*)d_in[10];
  const float* W_out = (const float*)d_in[11];
  const float* b_out = (const float*)d_in[12];
  float* out = (float*)d_out;
  char* ws = (char*)d_ws;

  (void)in_sizes; (void)n_in; (void)out_size; (void)ws_size;

  hipFuncSetAttribute((const void*)gru_main,
                      hipFuncAttributeMaxDynamicSharedMemorySize, SMEM_BYTES);

  hipLaunchKernelGGL(gru_init, dim3(512), dim3(256), 0, stream,
                     h0in, h1in, b_out, out, ws);

  void* args[] = { (void*)&x,
                   (void*)&W_ih1, (void*)&W_hh1, (void*)&b_ih1, (void*)&b_hh1,
                   (void*)&W_ih2, (void*)&W_hh2, (void*)&b_ih2, (void*)&b_hh2,
                   (void*)&W_out, (void*)&b_out,
                   (void*)&h0in, (void*)&h1in,
                   (void*)&out, (void*)&ws };
  hipLaunchCooperativeKernel((const void*)gru_main, dim3(NBLK), dim3(256),
                             args, SMEM_BYTES, stream);
}